// Round 3
// baseline (2312.150 us; speedup 1.0000x reference)
//
#include <hip/hip_runtime.h>
#include <cstdint>
#include <cstddef>

#define DI __device__ __forceinline__

#if defined(__has_builtin)
#if __has_builtin(__builtin_amdgcn_sdot4)
#define HAS_SDOT4 1
#endif
#endif

DI int dot4(unsigned a, unsigned b, int c) {
#ifdef HAS_SDOT4
  return __builtin_amdgcn_sdot4((int)a, (int)b, c, false);
#else
#pragma unroll
  for (int k = 0; k < 4; ++k)
    c += (int)(signed char)(a >> (8 * k)) * (int)(signed char)(b >> (8 * k));
  return c;
#endif
}

// ---------------- scalar block in workspace ----------------
struct Scal {
  unsigned max_x, max_w1, max_w2, max_wf1, max_wf2;  // float bits (abs-max, >=0)
  float s_in, sw1, sw2, swf1, swf2;
  int   max1; float s1;
  int   max2; float s2;
};

static constexpr int NX   = 32 * 3 * 224 * 224;     // 4,816,896
static constexpr int NP1  = 32 * 32 * 222 * 224;    // 50,921,472 padded conv1 outputs
static constexpr int NPIX = 222 * 224;              // 49,728 padded pixels per image
static constexpr int NCONV1 = 32 * 32 * 222 * 28;   // 6,365,184 threads (8 outputs each)
static constexpr int NCONV2 = 32 * 64 * 220 * 55;   // 24,780,800 (4 outputs per thread)

// ---------------- reduction helpers (blockDim == 256) ----------------
DI float wave_maxf(float v) { for (int o = 32; o; o >>= 1) v = fmaxf(v, __shfl_down(v, o, 64)); return v; }
DI int   wave_maxi(int v)   { for (int o = 32; o; o >>= 1) v = max(v, __shfl_down(v, o, 64));   return v; }
DI int   wave_sumi(int v)   { for (int o = 32; o; o >>= 1) v += __shfl_down(v, o, 64);          return v; }

DI float block_maxf(float v) {  // valid in thread 0; all values >= 0
  __shared__ float s[4];
  v = wave_maxf(v);
  int lane = threadIdx.x & 63, w = threadIdx.x >> 6;
  if (!lane) s[w] = v;
  __syncthreads();
  if (threadIdx.x < 64) {
    float t = (threadIdx.x < 4) ? s[threadIdx.x] : 0.f;
    v = wave_maxf(t);
  }
  return v;
}

DI int block_maxi(int v) {  // valid in thread 0; all values >= 0
  __shared__ int s[4];
  v = wave_maxi(v);
  int lane = threadIdx.x & 63, w = threadIdx.x >> 6;
  if (!lane) s[w] = v;
  __syncthreads();
  if (threadIdx.x < 64) {
    int t = (threadIdx.x < 4) ? s[threadIdx.x] : 0;
    v = wave_maxi(t);
  }
  return v;
}

// ---------------- stage kernels ----------------
__global__ void k_absmax_x(const float4* __restrict__ x, int n4, unsigned* slot) {
  float m = 0.f;
  for (int i = blockIdx.x * blockDim.x + threadIdx.x; i < n4; i += gridDim.x * blockDim.x) {
    float4 v = x[i];
    m = fmaxf(m, fmaxf(fmaxf(fabsf(v.x), fabsf(v.y)), fmaxf(fabsf(v.z), fabsf(v.w))));
  }
  m = block_maxf(m);
  if (!threadIdx.x) atomicMax(slot, __float_as_uint(m));
}

__global__ void k_absmax_w(const float* __restrict__ w1, const float* __restrict__ w2,
                           const float* __restrict__ wf1, const float* __restrict__ wf2,
                           Scal* sc) {
  const float* p; int n; unsigned* slot;
  if (blockIdx.x == 0)      { p = w1;  n = 864;   slot = &sc->max_w1; }
  else if (blockIdx.x == 1) { p = w2;  n = 18432; slot = &sc->max_w2; }
  else if (blockIdx.x == 2) { p = wf1; n = 8192;  slot = &sc->max_wf1; }
  else                      { p = wf2; n = 1280;  slot = &sc->max_wf2; }
  float m = 0.f;
  for (int i = threadIdx.x; i < n; i += blockDim.x) m = fmaxf(m, fabsf(p[i]));
  m = block_maxf(m);
  if (!threadIdx.x) atomicMax(slot, __float_as_uint(m));
}

__global__ void k_scales(Scal* sc) {
  sc->s_in = fmaxf(__uint_as_float(sc->max_x),  1e-8f) / 7.f;
  sc->sw1  = fmaxf(__uint_as_float(sc->max_w1), 1e-8f) / 7.f;
  sc->sw2  = fmaxf(__uint_as_float(sc->max_w2), 1e-8f) / 7.f;
  sc->swf1 = fmaxf(__uint_as_float(sc->max_wf1),1e-8f) / 7.f;
  sc->swf2 = fmaxf(__uint_as_float(sc->max_wf2),1e-8f) / 7.f;
}

// 4 floats -> 4 packed int8 codes per thread
__global__ void k_quant_x(const float4* __restrict__ x, unsigned* __restrict__ xq,
                          int n4, const Scal* __restrict__ sc) {
  float s = sc->s_in;
  int i = blockIdx.x * 256 + threadIdx.x;
  if (i >= n4) return;
  float4 v = x[i];
  float f[4] = {v.x, v.y, v.z, v.w};
  unsigned w = 0;
#pragma unroll
  for (int k = 0; k < 4; ++k) {
    float q = rintf(f[k] / s);
    q = fminf(fmaxf(q, -8.f), 7.f);
    w |= ((unsigned)((int)q & 255)) << (8 * k);
  }
  xq[i] = w;
}

// quantize w1 codes; pack w2 as [oc][kh][kw][ic] dwords (ic 4-per-dword); bias1 ints
__global__ void k_quant_w(const float* __restrict__ w1, const float* __restrict__ w2,
                          const float* __restrict__ b1, const Scal* __restrict__ sc,
                          signed char* __restrict__ qw1, unsigned* __restrict__ w2pk,
                          int* __restrict__ bint1) {
  int i = blockIdx.x * blockDim.x + threadIdx.x;
  if (i < 864) {
    float q = rintf(w1[i] / sc->sw1);
    q = fminf(fmaxf(q, -8.f), 7.f);
    qw1[i] = (signed char)(int)q;
  } else if (i < 864 + 4608) {
    int j = i - 864;           // output dword index
    int d = j & 7; int t = j >> 3;
    int kw = t % 3; t /= 3;
    int kh = t % 3; int oc = t / 3;
    float s = sc->sw2;
    unsigned w = 0;
#pragma unroll
    for (int k = 0; k < 4; ++k) {
      int ic = d * 4 + k;
      float q = rintf(w2[(oc * 32 + ic) * 9 + kh * 3 + kw] / s);
      q = fminf(fmaxf(q, -8.f), 7.f);
      w |= ((unsigned)((int)q & 255)) << (8 * k);
    }
    w2pk[j] = w;
  } else if (i < 864 + 4608 + 32) {
    int j = i - 5472;
    bint1[j] = (int)rintf(b1[j] / (sc->s_in * sc->sw1));
  }
}

// conv1 fused single pass: 3->32ch, 224^2 -> 222^2. 8 outputs/thread along ow.
// Stores raw int16 acc (padded row width 224, planar); block max of relu(acc).
__global__ void __launch_bounds__(256) k_conv1(
    const signed char* __restrict__ xq, const signed char* __restrict__ qw1,
    const int* __restrict__ bint1, short* __restrict__ y1acc, int* __restrict__ max1) {
  __shared__ signed char lw[864];
  int tid = threadIdx.x;
  if (tid < 216) ((int*)lw)[tid] = ((const int*)qw1)[tid];
  __syncthreads();

  int idx = blockIdx.x * 256 + tid;
  int g = idx % 28; int t = idx / 28;
  int oh = t % 222; t /= 222;
  int oc = t & 31, b = t >> 5;

  int w[9][3];
  {
    const signed char* wp = lw + oc * 27;
#pragma unroll
    for (int r = 0; r < 9; ++r)
#pragma unroll
      for (int k = 0; k < 3; ++k) w[r][k] = (int)wp[r * 3 + k];
  }
  int bias = bint1[oc];
  int acc[8];
#pragma unroll
  for (int j = 0; j < 8; ++j) acc[j] = bias;

  const signed char* xp = xq + ((b * 3) * 224 + oh) * 224 + g * 8;
#pragma unroll
  for (int ic = 0; ic < 3; ++ic) {
#pragma unroll
    for (int kh = 0; kh < 3; ++kh) {
      const signed char* xr = xp + (ic * 224 + kh) * 224;
      uint2 lo = *(const uint2*)xr;              // bytes 0..7   (8B aligned)
      unsigned hi = *(const unsigned*)(xr + 8);  // bytes 8..11  (4B aligned)
      int xv[10];
#pragma unroll
      for (int k = 0; k < 4; ++k) xv[k]     = (int)(signed char)(lo.x >> (8 * k));
#pragma unroll
      for (int k = 0; k < 4; ++k) xv[4 + k] = (int)(signed char)(lo.y >> (8 * k));
      xv[8] = (int)(signed char)(hi);
      xv[9] = (int)(signed char)(hi >> 8);
      int r = ic * 3 + kh;
      int w0 = w[r][0], w1 = w[r][1], w2 = w[r][2];
#pragma unroll
      for (int j = 0; j < 8; ++j)
        acc[j] += xv[j] * w0 + xv[j + 1] * w1 + xv[j + 2] * w2;
    }
  }

  size_t off = ((size_t)((b * 32 + oc) * 222 + oh)) * 224 + g * 8;
  uint4 st;
  st.x = ((unsigned)(unsigned short)acc[0]) | ((unsigned)(unsigned short)acc[1] << 16);
  st.y = ((unsigned)(unsigned short)acc[2]) | ((unsigned)(unsigned short)acc[3] << 16);
  st.z = ((unsigned)(unsigned short)acc[4]) | ((unsigned)(unsigned short)acc[5] << 16);
  st.w = ((unsigned)(unsigned short)acc[6]) | ((unsigned)(unsigned short)acc[7] << 16);
  *(uint4*)(y1acc + off) = st;

  int m = 0;
#pragma unroll
  for (int j = 0; j < 8; ++j) if (g * 8 + j < 222) m = max(m, acc[j]);
  m = block_maxi(m);
  if (!tid) atomicMax(max1, m);
}

__global__ void k_fin1(Scal* sc, const float* __restrict__ b2, int* __restrict__ bint2) {
  float sc1 = sc->s_in * sc->sw1;
  float s1 = fmaxf((float)sc->max1 * sc1, 1e-8f) / 15.f;
  if (!threadIdx.x) sc->s1 = s1;
  float sb = s1 * sc->sw2;
  bint2[threadIdx.x] = (int)rintf(b2[threadIdx.x] / sb);
}

// int16 planar acc -> NHWC uint8 relu4 codes (32 ic bytes contiguous per pixel)
__global__ void k_requant_t(const short* __restrict__ y1acc, const Scal* __restrict__ sc,
                            unsigned char* __restrict__ y1n) {
  int p = blockIdx.x * 256 + threadIdx.x;  // pixel within image (padded space)
  int b = blockIdx.y;
  if (p >= NPIX) return;
  float sc1 = sc->s_in * sc->sw1, s1 = sc->s1;
  const short* base = y1acc + (size_t)b * 32 * NPIX + p;
  unsigned w[8] = {0, 0, 0, 0, 0, 0, 0, 0};
#pragma unroll
  for (int oc = 0; oc < 32; ++oc) {
    int a = (int)base[(size_t)oc * NPIX];
    float y = (float)a * sc1;
    float q = rintf(y / s1);
    q = fminf(fmaxf(q, 0.f), 15.f);
    w[oc >> 2] |= ((unsigned)(int)q) << (8 * (oc & 3));
  }
  uint4* dst = (uint4*)(y1n + ((size_t)b * NPIX + p) * 32);
  dst[0] = make_uint4(w[0], w[1], w[2], w[3]);
  dst[1] = make_uint4(w[4], w[5], w[6], w[7]);
}

// conv2 via dot4: 32->64ch, 222^2 -> 220^2, NHWC input. 4 outputs/thread along ow.
__global__ void __launch_bounds__(256) k_conv2(
    const unsigned char* __restrict__ y1n, const unsigned* __restrict__ w2pk,
    const int* __restrict__ bint2, unsigned short* __restrict__ y2, int* __restrict__ max2) {
  int idx = blockIdx.x * 256 + threadIdx.x;
  int g = idx % 55; int t = idx / 55;
  int oh = t % 220; t /= 220;
  int oc = t & 63, b = t >> 6;
  int bias = bint2[oc];
  int acc[4] = {bias, bias, bias, bias};
  const unsigned* wbase = w2pk + oc * 72;
#pragma unroll
  for (int kh = 0; kh < 3; ++kh) {
    const uint4* xr = (const uint4*)(y1n + ((size_t)((b * 222 + oh + kh) * 224 + g * 4)) * 32);
    uint4 xv[12];  // 6 cols x 32B
#pragma unroll
    for (int c = 0; c < 12; ++c) xv[c] = xr[c];
    const unsigned* xu = (const unsigned*)xv;
#pragma unroll
    for (int kw = 0; kw < 3; ++kw) {
      const uint4* wp = (const uint4*)(wbase + (kh * 3 + kw) * 8);
      uint4 wa = wp[0], wb = wp[1];
#pragma unroll
      for (int j = 0; j < 4; ++j) {
        const unsigned* xc = xu + (j + kw) * 8;
        int a = acc[j];
        a = dot4(xc[0], wa.x, a); a = dot4(xc[1], wa.y, a);
        a = dot4(xc[2], wa.z, a); a = dot4(xc[3], wa.w, a);
        a = dot4(xc[4], wb.x, a); a = dot4(xc[5], wb.y, a);
        a = dot4(xc[6], wb.z, a); a = dot4(xc[7], wb.w, a);
        acc[j] = a;
      }
    }
  }
  size_t off = ((size_t)(b * 64 + oc) * 220 + oh) * 220 + (size_t)g * 4;
  uint2 st;
  st.x = (unsigned)min(max(acc[0], 0), 65535) | ((unsigned)min(max(acc[1], 0), 65535) << 16);
  st.y = (unsigned)min(max(acc[2], 0), 65535) | ((unsigned)min(max(acc[3], 0), 65535) << 16);
  *(uint2*)(y2 + off) = st;
  int m = max(max(acc[0], acc[1]), max(acc[2], acc[3]));
  m = block_maxi(max(m, 0));
  if (!threadIdx.x) atomicMax(max2, m);
}

__global__ void k_fin2(Scal* sc) {
  sc->s2 = fmaxf((float)sc->max2 * (sc->s1 * sc->sw2), 1e-8f) / 15.f;
}

// quantize y2 + global average pool per (b, oc); vectorized uint4 (8 x u16) loads
__global__ void k_pool(const unsigned short* __restrict__ y2, const Scal* __restrict__ sc,
                       float* __restrict__ pooled) {
  int bc = blockIdx.x;  // 0..2047 = b*64+oc
  const unsigned short* p = y2 + (size_t)bc * 48400;
  float sc2 = sc->s1 * sc->sw2, s2 = sc->s2;
  int sum = 0;
  for (int i = threadIdx.x; i < 6050; i += 256) {
    uint4 v = *(const uint4*)(p + (size_t)i * 8);
    unsigned words[4] = {v.x, v.y, v.z, v.w};
#pragma unroll
    for (int k = 0; k < 8; ++k) {
      int a = (int)(unsigned short)(words[k >> 1] >> (16 * (k & 1)));
      float y = (float)a * sc2;
      float q = rintf(y / s2);
      q = fminf(fmaxf(q, 0.f), 15.f);
      sum += (int)q;
    }
  }
  sum = wave_sumi(sum);
  __shared__ int s[4];
  int lane = threadIdx.x & 63, w = threadIdx.x >> 6;
  if (!lane) s[w] = sum;
  __syncthreads();
  if (threadIdx.x < 64) {
    int v = (threadIdx.x < 4) ? s[threadIdx.x] : 0;
    v = wave_sumi(v);
    if (!threadIdx.x) pooled[bc] = ((float)v * s2) / 48400.0f;
  }
}

// whole FC head + log_softmax in one block
__global__ void k_fc(const float* __restrict__ pooled, const float* __restrict__ wf1,
                     const float* __restrict__ bf1, const float* __restrict__ wf2,
                     const float* __restrict__ bf2, const Scal* __restrict__ sc,
                     float* __restrict__ out) {
  __shared__ float pl[2048];
  __shared__ float wq1[8192];
  __shared__ float y3[4096];
  __shared__ float zz[320];
  __shared__ float s3sh;
  int tid = threadIdx.x;
  float swf1 = sc->swf1, swf2 = sc->swf2, s2 = sc->s2;
  (void)s2;
  for (int i = tid; i < 2048; i += 256) pl[i] = pooled[i];
  for (int i = tid; i < 8192; i += 256) {
    float q = rintf(wf1[i] / swf1);
    q = fminf(fmaxf(q, -8.f), 7.f);
    wq1[i] = q * swf1;
  }
  __syncthreads();
  float sb1 = sc->s2 * swf1;
  float lmax = 0.f;
  for (int o = tid; o < 4096; o += 256) {
    int b = o >> 7, j = o & 127;
    float acc = rintf(bf1[j] / sb1) * sb1;
    const float* wrow = &wq1[j * 64];
    const float* xrow = &pl[b * 64];
#pragma unroll 16
    for (int k = 0; k < 64; ++k) acc += xrow[k] * wrow[k];
    float r = fmaxf(acc, 0.f);
    y3[o] = r;
    lmax = fmaxf(lmax, r);
  }
  float m = block_maxf(lmax);  // contains a __syncthreads (after y3 writes)
  if (!tid) s3sh = fmaxf(m, 1e-8f) / 15.f;
  __syncthreads();
  float s3 = s3sh;
  float sb2 = s3 * swf2;
  for (int o = tid; o < 320; o += 256) {
    int b = o / 10, j = o - b * 10;
    float acc = rintf(bf2[j] / sb2) * sb2;
    const float* yy = &y3[b * 128];
    const float* wrow = &wf2[j * 128];
    for (int k = 0; k < 128; ++k) {
      float q = rintf(yy[k] / s3);
      q = fminf(fmaxf(q, 0.f), 15.f);
      float wv = rintf(wrow[k] / swf2);
      wv = fminf(fmaxf(wv, -8.f), 7.f);
      acc += (q * s3) * (wv * swf2);
    }
    zz[o] = acc;
  }
  __syncthreads();
  if (tid < 32) {
    const float* z = &zz[tid * 10];
    float mm = z[0];
    for (int k = 1; k < 10; ++k) mm = fmaxf(mm, z[k]);
    float ssum = 0.f;
    for (int k = 0; k < 10; ++k) ssum += expf(z[k] - mm);
    float l = mm + logf(ssum);
    for (int k = 0; k < 10; ++k) out[tid * 10 + k] = z[k] - l;
  }
}

extern "C" void kernel_launch(void* const* d_in, const int* in_sizes, int n_in,
                              void* d_out, int out_size, void* d_ws, size_t ws_size,
                              hipStream_t stream) {
  const float* x   = (const float*)d_in[0];
  const float* w1  = (const float*)d_in[1];
  const float* b1  = (const float*)d_in[2];
  const float* w2  = (const float*)d_in[3];
  const float* b2  = (const float*)d_in[4];
  const float* wf1 = (const float*)d_in[5];
  const float* bf1 = (const float*)d_in[6];
  const float* wf2 = (const float*)d_in[7];
  const float* bf2 = (const float*)d_in[8];
  float* out = (float*)d_out;

  char* ws = (char*)d_ws;
  Scal* sc = (Scal*)ws;
  size_t off = 1024;
  signed char* xq = (signed char*)(ws + off);   off += (size_t)NX + 256;  // +slack for 12B edge reads
  off = (off + 255) & ~(size_t)255;
  signed char* qw1 = (signed char*)(ws + off);  off += 1024;
  unsigned* w2pk = (unsigned*)(ws + off);       off += 4608 * 4;          // [oc][kh][kw][ic/4]
  int* bint1 = (int*)(ws + off);                off += 256;
  int* bint2 = (int*)(ws + off);                off += 256;
  unsigned char* y1n = (unsigned char*)(ws + off); off += (size_t)NP1;    // NHWC codes
  off = (off + 255) & ~(size_t)255;
  float* pooled = (float*)(ws + off);           off += 8192;
  // y2 region (198 MB) doubles as y1acc (102 MB) — y1acc fully consumed before conv2 writes y2
  unsigned short* y2 = (unsigned short*)(ws + off);
  short* y1acc = (short*)(ws + off);            off += (size_t)32 * 64 * 220 * 220 * 2;
  (void)ws_size; (void)in_sizes; (void)n_in; (void)out_size;

  hipMemsetAsync(sc, 0, 1024, stream);
  k_absmax_x<<<1024, 256, 0, stream>>>((const float4*)x, NX / 4, &sc->max_x);
  k_absmax_w<<<4, 256, 0, stream>>>(w1, w2, wf1, wf2, sc);
  k_scales<<<1, 1, 0, stream>>>(sc);
  k_quant_x<<<NX / 4 / 256, 256, 0, stream>>>((const float4*)x, (unsigned*)xq, NX / 4, sc);
  k_quant_w<<<22, 256, 0, stream>>>(w1, w2, b1, sc, qw1, w2pk, bint1);
  k_conv1<<<NCONV1 / 256, 256, 0, stream>>>(xq, qw1, bint1, y1acc, &sc->max1);
  k_fin1<<<1, 64, 0, stream>>>(sc, b2, bint2);
  k_requant_t<<<dim3(195, 32), 256, 0, stream>>>(y1acc, sc, y1n);
  k_conv2<<<NCONV2 / 256, 256, 0, stream>>>(y1n, w2pk, bint2, y2, &sc->max2);
  k_fin2<<<1, 1, 0, stream>>>(sc);
  k_pool<<<2048, 256, 0, stream>>>(y2, sc, pooled);
  k_fc<<<1, 256, 0, stream>>>(pooled, wf1, bf1, wf2, bf2, sc, out);
}

// Round 4
// 1675.379 us; speedup vs baseline: 1.3801x; 1.3801x over previous
//
#include <hip/hip_runtime.h>
#include <cstdint>
#include <cstddef>

#define DI __device__ __forceinline__

#if defined(__has_builtin)
#if __has_builtin(__builtin_amdgcn_sdot4)
#define HAS_SDOT4 1
#endif
#endif

DI int dot4(unsigned a, unsigned b, int c) {
#ifdef HAS_SDOT4
  return __builtin_amdgcn_sdot4((int)a, (int)b, c, false);
#else
#pragma unroll
  for (int k = 0; k < 4; ++k)
    c += (int)(signed char)(a >> (8 * k)) * (int)(signed char)(b >> (8 * k));
  return c;
#endif
}

// ---------------- scalar block in workspace ----------------
struct Scal {
  unsigned max_x, max_w1, max_w2, max_wf1, max_wf2;  // float bits (abs-max, >=0)
  float s_in, sw1, sw2, swf1, swf2;
  int   max1; float s1;
  int   max2; float s2;
};

static constexpr int NX   = 32 * 3 * 224 * 224;     // 4,816,896
static constexpr int NP1  = 32 * 32 * 222 * 224;    // 50,921,472 padded conv1 outputs
static constexpr int NPIX = 222 * 224;              // 49,728 padded pixels per image
static constexpr int NCONV1 = 32 * 32 * 222 * 28;   // 6,365,184 threads (8 outputs each)
static constexpr int NW2 = 32 * 220 * 28;           // conv2 waves: one wave = 64 oc x 8 px

// ---------------- reduction helpers (blockDim == 256) ----------------
DI float wave_maxf(float v) { for (int o = 32; o; o >>= 1) v = fmaxf(v, __shfl_down(v, o, 64)); return v; }
DI int   wave_maxi(int v)   { for (int o = 32; o; o >>= 1) v = max(v, __shfl_down(v, o, 64));   return v; }
DI int   wave_sumi(int v)   { for (int o = 32; o; o >>= 1) v += __shfl_down(v, o, 64);          return v; }

DI float block_maxf(float v) {  // valid in thread 0; all values >= 0
  __shared__ float s[4];
  v = wave_maxf(v);
  int lane = threadIdx.x & 63, w = threadIdx.x >> 6;
  if (!lane) s[w] = v;
  __syncthreads();
  if (threadIdx.x < 64) {
    float t = (threadIdx.x < 4) ? s[threadIdx.x] : 0.f;
    v = wave_maxf(t);
  }
  return v;
}

DI int block_maxi(int v) {  // valid in thread 0; all values >= 0
  __shared__ int s[4];
  v = wave_maxi(v);
  int lane = threadIdx.x & 63, w = threadIdx.x >> 6;
  if (!lane) s[w] = v;
  __syncthreads();
  if (threadIdx.x < 64) {
    int t = (threadIdx.x < 4) ? s[threadIdx.x] : 0;
    v = wave_maxi(t);
  }
  return v;
}

// ---------------- stage kernels ----------------
__global__ void k_absmax_x(const float4* __restrict__ x, int n4, unsigned* slot) {
  float m = 0.f;
  for (int i = blockIdx.x * blockDim.x + threadIdx.x; i < n4; i += gridDim.x * blockDim.x) {
    float4 v = x[i];
    m = fmaxf(m, fmaxf(fmaxf(fabsf(v.x), fabsf(v.y)), fmaxf(fabsf(v.z), fabsf(v.w))));
  }
  m = block_maxf(m);
  if (!threadIdx.x) atomicMax(slot, __float_as_uint(m));
}

__global__ void k_absmax_w(const float* __restrict__ w1, const float* __restrict__ w2,
                           const float* __restrict__ wf1, const float* __restrict__ wf2,
                           Scal* sc) {
  const float* p; int n; unsigned* slot;
  if (blockIdx.x == 0)      { p = w1;  n = 864;   slot = &sc->max_w1; }
  else if (blockIdx.x == 1) { p = w2;  n = 18432; slot = &sc->max_w2; }
  else if (blockIdx.x == 2) { p = wf1; n = 8192;  slot = &sc->max_wf1; }
  else                      { p = wf2; n = 1280;  slot = &sc->max_wf2; }
  float m = 0.f;
  for (int i = threadIdx.x; i < n; i += blockDim.x) m = fmaxf(m, fabsf(p[i]));
  m = block_maxf(m);
  if (!threadIdx.x) atomicMax(slot, __float_as_uint(m));
}

__global__ void k_scales(Scal* sc) {
  sc->s_in = fmaxf(__uint_as_float(sc->max_x),  1e-8f) / 7.f;
  sc->sw1  = fmaxf(__uint_as_float(sc->max_w1), 1e-8f) / 7.f;
  sc->sw2  = fmaxf(__uint_as_float(sc->max_w2), 1e-8f) / 7.f;
  sc->swf1 = fmaxf(__uint_as_float(sc->max_wf1),1e-8f) / 7.f;
  sc->swf2 = fmaxf(__uint_as_float(sc->max_wf2),1e-8f) / 7.f;
}

// 4 floats -> 4 packed int8 codes per thread
__global__ void k_quant_x(const float4* __restrict__ x, unsigned* __restrict__ xq,
                          int n4, const Scal* __restrict__ sc) {
  float s = sc->s_in;
  int i = blockIdx.x * 256 + threadIdx.x;
  if (i >= n4) return;
  float4 v = x[i];
  float f[4] = {v.x, v.y, v.z, v.w};
  unsigned w = 0;
#pragma unroll
  for (int k = 0; k < 4; ++k) {
    float q = rintf(f[k] / s);
    q = fminf(fmaxf(q, -8.f), 7.f);
    w |= ((unsigned)((int)q & 255)) << (8 * k);
  }
  xq[i] = w;
}

// quantize w1 codes; pack w2 as [oc][kh][kw][ic] dwords (ic 4-per-dword); bias1 ints
__global__ void k_quant_w(const float* __restrict__ w1, const float* __restrict__ w2,
                          const float* __restrict__ b1, const Scal* __restrict__ sc,
                          signed char* __restrict__ qw1, unsigned* __restrict__ w2pk,
                          int* __restrict__ bint1) {
  int i = blockIdx.x * blockDim.x + threadIdx.x;
  if (i < 864) {
    float q = rintf(w1[i] / sc->sw1);
    q = fminf(fmaxf(q, -8.f), 7.f);
    qw1[i] = (signed char)(int)q;
  } else if (i < 864 + 4608) {
    int j = i - 864;           // output dword index
    int d = j & 7; int t = j >> 3;
    int kw = t % 3; t /= 3;
    int kh = t % 3; int oc = t / 3;
    float s = sc->sw2;
    unsigned w = 0;
#pragma unroll
    for (int k = 0; k < 4; ++k) {
      int ic = d * 4 + k;
      float q = rintf(w2[(oc * 32 + ic) * 9 + kh * 3 + kw] / s);
      q = fminf(fmaxf(q, -8.f), 7.f);
      w |= ((unsigned)((int)q & 255)) << (8 * k);
    }
    w2pk[j] = w;
  } else if (i < 864 + 4608 + 32) {
    int j = i - 5472;
    bint1[j] = (int)rintf(b1[j] / (sc->s_in * sc->sw1));
  }
}

// conv1 fused single pass: 3->32ch, 224^2 -> 222^2. 8 outputs/thread along ow.
// Stores raw int16 acc (padded row width 224, planar); block max of relu(acc).
__global__ void __launch_bounds__(256) k_conv1(
    const signed char* __restrict__ xq, const signed char* __restrict__ qw1,
    const int* __restrict__ bint1, short* __restrict__ y1acc, int* __restrict__ max1) {
  __shared__ signed char lw[864];
  int tid = threadIdx.x;
  if (tid < 216) ((int*)lw)[tid] = ((const int*)qw1)[tid];
  __syncthreads();

  int idx = blockIdx.x * 256 + tid;
  int g = idx % 28; int t = idx / 28;
  int oh = t % 222; t /= 222;
  int oc = t & 31, b = t >> 5;

  int w[9][3];
  {
    const signed char* wp = lw + oc * 27;
#pragma unroll
    for (int r = 0; r < 9; ++r)
#pragma unroll
      for (int k = 0; k < 3; ++k) w[r][k] = (int)wp[r * 3 + k];
  }
  int bias = bint1[oc];
  int acc[8];
#pragma unroll
  for (int j = 0; j < 8; ++j) acc[j] = bias;

  const signed char* xp = xq + ((b * 3) * 224 + oh) * 224 + g * 8;
#pragma unroll
  for (int ic = 0; ic < 3; ++ic) {
#pragma unroll
    for (int kh = 0; kh < 3; ++kh) {
      const signed char* xr = xp + (ic * 224 + kh) * 224;
      uint2 lo = *(const uint2*)xr;              // bytes 0..7   (8B aligned)
      unsigned hi = *(const unsigned*)(xr + 8);  // bytes 8..11  (4B aligned)
      int xv[10];
#pragma unroll
      for (int k = 0; k < 4; ++k) xv[k]     = (int)(signed char)(lo.x >> (8 * k));
#pragma unroll
      for (int k = 0; k < 4; ++k) xv[4 + k] = (int)(signed char)(lo.y >> (8 * k));
      xv[8] = (int)(signed char)(hi);
      xv[9] = (int)(signed char)(hi >> 8);
      int r = ic * 3 + kh;
      int w0 = w[r][0], w1 = w[r][1], w2 = w[r][2];
#pragma unroll
      for (int j = 0; j < 8; ++j)
        acc[j] += xv[j] * w0 + xv[j + 1] * w1 + xv[j + 2] * w2;
    }
  }

  size_t off = ((size_t)((b * 32 + oc) * 222 + oh)) * 224 + g * 8;
  uint4 st;
  st.x = ((unsigned)(unsigned short)acc[0]) | ((unsigned)(unsigned short)acc[1] << 16);
  st.y = ((unsigned)(unsigned short)acc[2]) | ((unsigned)(unsigned short)acc[3] << 16);
  st.z = ((unsigned)(unsigned short)acc[4]) | ((unsigned)(unsigned short)acc[5] << 16);
  st.w = ((unsigned)(unsigned short)acc[6]) | ((unsigned)(unsigned short)acc[7] << 16);
  *(uint4*)(y1acc + off) = st;

  int m = 0;
#pragma unroll
  for (int j = 0; j < 8; ++j) if (g * 8 + j < 222) m = max(m, acc[j]);
  m = block_maxi(m);
  if (!tid) atomicMax(max1, m);
}

__global__ void k_fin1(Scal* sc, const float* __restrict__ b2, int* __restrict__ bint2) {
  float sc1 = sc->s_in * sc->sw1;
  float s1 = fmaxf((float)sc->max1 * sc1, 1e-8f) / 15.f;
  if (!threadIdx.x) sc->s1 = s1;
  float sb = s1 * sc->sw2;
  bint2[threadIdx.x] = (int)rintf(b2[threadIdx.x] / sb);
}

// int16 planar acc -> NHWC uint8 relu4 codes (32 ic bytes contiguous per pixel)
__global__ void k_requant_t(const short* __restrict__ y1acc, const Scal* __restrict__ sc,
                            unsigned char* __restrict__ y1n) {
  int p = blockIdx.x * 256 + threadIdx.x;  // pixel within image (padded space)
  int b = blockIdx.y;
  if (p >= NPIX) return;
  float sc1 = sc->s_in * sc->sw1, s1 = sc->s1;
  const short* base = y1acc + (size_t)b * 32 * NPIX + p;
  unsigned w[8] = {0, 0, 0, 0, 0, 0, 0, 0};
#pragma unroll
  for (int oc = 0; oc < 32; ++oc) {
    int a = (int)base[(size_t)oc * NPIX];
    float y = (float)a * sc1;
    float q = rintf(y / s1);
    q = fminf(fmaxf(q, 0.f), 15.f);
    w[oc >> 2] |= ((unsigned)(int)q) << (8 * (oc & 3));
  }
  uint4* dst = (uint4*)(y1n + ((size_t)b * NPIX + p) * 32);
  dst[0] = make_uint4(w[0], w[1], w[2], w[3]);
  dst[1] = make_uint4(w[4], w[5], w[6], w[7]);
}

// conv2 via dot4: 32->64ch, NHWC in/out. One wave = 64 oc x 8 px group.
// Input loads wave-uniform (broadcast); weights LDS-staged (stride 76 dwords,
// conflict-free b128); y2 stored NHWC so u16 stores coalesce across oc lanes.
__global__ void __launch_bounds__(256) k_conv2(
    const unsigned char* __restrict__ y1n, const unsigned* __restrict__ w2pk,
    const int* __restrict__ bint2, unsigned short* __restrict__ y2, int* __restrict__ max2) {
  __shared__ unsigned lw[64 * 76];
  int tid = threadIdx.x;
  for (int i = tid; i < 4608; i += 256) {
    int oc = i / 72, d = i - oc * 72;
    lw[oc * 76 + d] = w2pk[i];
  }
  __syncthreads();

  int lane = tid & 63;                       // oc
  int wv = blockIdx.x * 4 + (tid >> 6);      // global wave id
  int g = wv % 28; int t = wv / 28;
  int oh = t % 220; int b = t / 220;
  int ow0 = g * 8;

  int bias = bint2[lane];
  int acc[8];
#pragma unroll
  for (int j = 0; j < 8; ++j) acc[j] = bias;

  const unsigned* wp = lw + lane * 76;
#pragma unroll
  for (int kh = 0; kh < 3; ++kh) {
    const unsigned char* row = y1n + ((size_t)((b * 222 + oh + kh) * 224 + ow0)) * 32;
#pragma unroll
    for (int dq = 0; dq < 2; ++dq) {
      uint4 in[10];
#pragma unroll
      for (int c = 0; c < 10; ++c)
        in[c] = *(const uint4*)(row + c * 32 + dq * 16);
#pragma unroll
      for (int kw = 0; kw < 3; ++kw) {
        uint4 w = *(const uint4*)(wp + (kh * 3 + kw) * 8 + dq * 4);
#pragma unroll
        for (int j = 0; j < 8; ++j) {
          int a = acc[j];
          a = dot4(in[j + kw].x, w.x, a);
          a = dot4(in[j + kw].y, w.y, a);
          a = dot4(in[j + kw].z, w.z, a);
          a = dot4(in[j + kw].w, w.w, a);
          acc[j] = a;
        }
      }
    }
  }

  size_t obase = (size_t)(b * 220 + oh) * 220;
  int m = 0;
#pragma unroll
  for (int j = 0; j < 8; ++j) {
    int ow = ow0 + j;
    if (ow < 220) {
      int a = acc[j];
      y2[(obase + ow) * 64 + lane] = (unsigned short)min(max(a, 0), 65535);
      m = max(m, a);
    }
  }
  m = block_maxi(max(m, 0));
  if (!tid) atomicMax(max2, m);
}

__global__ void k_fin2(Scal* sc) {
  sc->s2 = fmaxf((float)sc->max2 * (sc->s1 * sc->sw2), 1e-8f) / 15.f;
}

// quantize y2 (NHWC) + global average pool: int sums accumulated per (b, oc)
__global__ void k_pool(const unsigned short* __restrict__ y2, const Scal* __restrict__ sc,
                       int* __restrict__ pooled_i) {
  int b = blockIdx.x;        // 0..31
  int chunk = blockIdx.y;    // 0..10 (4400 px each, 11*4400 = 48400)
  int oc = threadIdx.x & 63;
  int pr = threadIdx.x >> 6; // 0..3
  float sc2 = sc->s1 * sc->sw2, s2 = sc->s2;
  const unsigned short* base = y2 + ((size_t)b * 48400 + (size_t)chunk * 4400) * 64 + oc;
  int sum = 0;
  for (int i = pr; i < 4400; i += 4) {
    int a = (int)base[(size_t)i * 64];
    float y = (float)a * sc2;
    float q = rintf(y / s2);
    q = fminf(fmaxf(q, 0.f), 15.f);
    sum += (int)q;
  }
  __shared__ int red[4][64];
  red[pr][oc] = sum;
  __syncthreads();
  if (pr == 0) {
    int t = red[0][oc] + red[1][oc] + red[2][oc] + red[3][oc];
    atomicAdd(&pooled_i[b * 64 + oc], t);
  }
}

// whole FC head + log_softmax in one block
__global__ void k_fc(const int* __restrict__ pooled_i, const float* __restrict__ wf1,
                     const float* __restrict__ bf1, const float* __restrict__ wf2,
                     const float* __restrict__ bf2, const Scal* __restrict__ sc,
                     float* __restrict__ out) {
  __shared__ float pl[2048];
  __shared__ float wq1[8192];
  __shared__ float y3[4096];
  __shared__ float zz[320];
  __shared__ float s3sh;
  int tid = threadIdx.x;
  float swf1 = sc->swf1, swf2 = sc->swf2, s2 = sc->s2;
  for (int i = tid; i < 2048; i += 256) pl[i] = (float)pooled_i[i] * s2 / 48400.0f;
  for (int i = tid; i < 8192; i += 256) {
    float q = rintf(wf1[i] / swf1);
    q = fminf(fmaxf(q, -8.f), 7.f);
    wq1[i] = q * swf1;
  }
  __syncthreads();
  float sb1 = s2 * swf1;
  float lmax = 0.f;
  for (int o = tid; o < 4096; o += 256) {
    int b = o >> 7, j = o & 127;
    float acc = rintf(bf1[j] / sb1) * sb1;
    const float* wrow = &wq1[j * 64];
    const float* xrow = &pl[b * 64];
#pragma unroll 16
    for (int k = 0; k < 64; ++k) acc += xrow[k] * wrow[k];
    float r = fmaxf(acc, 0.f);
    y3[o] = r;
    lmax = fmaxf(lmax, r);
  }
  float m = block_maxf(lmax);  // contains a __syncthreads (after y3 writes)
  if (!tid) s3sh = fmaxf(m, 1e-8f) / 15.f;
  __syncthreads();
  float s3 = s3sh;
  float sb2 = s3 * swf2;
  for (int o = tid; o < 320; o += 256) {
    int b = o / 10, j = o - b * 10;
    float acc = rintf(bf2[j] / sb2) * sb2;
    const float* yy = &y3[b * 128];
    const float* wrow = &wf2[j * 128];
    for (int k = 0; k < 128; ++k) {
      float q = rintf(yy[k] / s3);
      q = fminf(fmaxf(q, 0.f), 15.f);
      float wv = rintf(wrow[k] / swf2);
      wv = fminf(fmaxf(wv, -8.f), 7.f);
      acc += (q * s3) * (wv * swf2);
    }
    zz[o] = acc;
  }
  __syncthreads();
  if (tid < 32) {
    const float* z = &zz[tid * 10];
    float mm = z[0];
    for (int k = 1; k < 10; ++k) mm = fmaxf(mm, z[k]);
    float ssum = 0.f;
    for (int k = 0; k < 10; ++k) ssum += expf(z[k] - mm);
    float l = mm + logf(ssum);
    for (int k = 0; k < 10; ++k) out[tid * 10 + k] = z[k] - l;
  }
}

extern "C" void kernel_launch(void* const* d_in, const int* in_sizes, int n_in,
                              void* d_out, int out_size, void* d_ws, size_t ws_size,
                              hipStream_t stream) {
  const float* x   = (const float*)d_in[0];
  const float* w1  = (const float*)d_in[1];
  const float* b1  = (const float*)d_in[2];
  const float* w2  = (const float*)d_in[3];
  const float* b2  = (const float*)d_in[4];
  const float* wf1 = (const float*)d_in[5];
  const float* bf1 = (const float*)d_in[6];
  const float* wf2 = (const float*)d_in[7];
  const float* bf2 = (const float*)d_in[8];
  float* out = (float*)d_out;

  char* ws = (char*)d_ws;
  Scal* sc = (Scal*)ws;
  size_t off = 1024;
  signed char* xq = (signed char*)(ws + off);   off += (size_t)NX + 256;  // +slack for edge reads
  off = (off + 255) & ~(size_t)255;
  signed char* qw1 = (signed char*)(ws + off);  off += 1024;
  unsigned* w2pk = (unsigned*)(ws + off);       off += 4608 * 4;          // [oc][kh][kw][ic/4]
  int* bint1 = (int*)(ws + off);                off += 256;
  int* bint2 = (int*)(ws + off);                off += 256;
  unsigned char* y1n = (unsigned char*)(ws + off); off += (size_t)NP1;    // NHWC codes
  off = (off + 255) & ~(size_t)255;
  int* pooled_i = (int*)(ws + off);             off += 8192;
  // y2 region (198 MB, NHWC u16) doubles as y1acc (102 MB) — y1acc fully consumed before conv2 writes y2
  unsigned short* y2 = (unsigned short*)(ws + off);
  short* y1acc = (short*)(ws + off);            off += (size_t)32 * 220 * 220 * 64 * 2;
  (void)ws_size; (void)in_sizes; (void)n_in; (void)out_size;

  hipMemsetAsync(sc, 0, 1024, stream);
  hipMemsetAsync(pooled_i, 0, 8192, stream);
  k_absmax_x<<<1024, 256, 0, stream>>>((const float4*)x, NX / 4, &sc->max_x);
  k_absmax_w<<<4, 256, 0, stream>>>(w1, w2, wf1, wf2, sc);
  k_scales<<<1, 1, 0, stream>>>(sc);
  k_quant_x<<<NX / 4 / 256, 256, 0, stream>>>((const float4*)x, (unsigned*)xq, NX / 4, sc);
  k_quant_w<<<22, 256, 0, stream>>>(w1, w2, b1, sc, qw1, w2pk, bint1);
  k_conv1<<<NCONV1 / 256, 256, 0, stream>>>(xq, qw1, bint1, y1acc, &sc->max1);
  k_fin1<<<1, 64, 0, stream>>>(sc, b2, bint2);
  k_requant_t<<<dim3(195, 32), 256, 0, stream>>>(y1acc, sc, y1n);
  k_conv2<<<NW2 / 4, 256, 0, stream>>>(y1n, w2pk, bint2, y2, &sc->max2);
  k_fin2<<<1, 1, 0, stream>>>(sc);
  k_pool<<<dim3(32, 11), 256, 0, stream>>>(y2, sc, pooled_i);
  k_fc<<<1, 256, 0, stream>>>(pooled_i, wf1, bf1, wf2, bf2, sc, out);
}

// Round 5
// 903.495 us; speedup vs baseline: 2.5591x; 1.8543x over previous
//
#include <hip/hip_runtime.h>
#include <cstdint>
#include <cstddef>

#define DI __device__ __forceinline__

typedef int v4i  __attribute__((ext_vector_type(4)));
typedef int v16i __attribute__((ext_vector_type(16)));

// ---------------- scalar block in workspace ----------------
struct Scal {
  unsigned max_x, max_w1, max_w2, max_wf1, max_wf2;  // float bits (abs-max, >=0)
  float s_in, sw1, sw2, swf1, swf2;
  int   max1; float s1;
  int   max2; float s2;
};

static constexpr int NX   = 32 * 3 * 224 * 224;     // 4,816,896
static constexpr int NP1  = 32 * 32 * 222 * 224;    // 50,921,472 padded conv1 outputs
static constexpr int NPIX = 222 * 224;              // 49,728 padded pixels per image
static constexpr int NCONV1 = 32 * 32 * 222 * 28;   // 6,365,184 threads (8 outputs each)
static constexpr int NW2 = 32 * 220 * 7;            // conv2 waves: 32 px x 64 oc tiles

// ---------------- reduction helpers (blockDim == 256) ----------------
DI float wave_maxf(float v) { for (int o = 32; o; o >>= 1) v = fmaxf(v, __shfl_down(v, o, 64)); return v; }
DI int   wave_maxi(int v)   { for (int o = 32; o; o >>= 1) v = max(v, __shfl_down(v, o, 64));   return v; }

DI float block_maxf(float v) {  // valid in thread 0; all values >= 0
  __shared__ float s[4];
  v = wave_maxf(v);
  int lane = threadIdx.x & 63, w = threadIdx.x >> 6;
  if (!lane) s[w] = v;
  __syncthreads();
  if (threadIdx.x < 64) {
    float t = (threadIdx.x < 4) ? s[threadIdx.x] : 0.f;
    v = wave_maxf(t);
  }
  return v;
}

DI int block_maxi(int v) {  // valid in thread 0; all values >= 0
  __shared__ int s[4];
  v = wave_maxi(v);
  int lane = threadIdx.x & 63, w = threadIdx.x >> 6;
  if (!lane) s[w] = v;
  __syncthreads();
  if (threadIdx.x < 64) {
    int t = (threadIdx.x < 4) ? s[threadIdx.x] : 0;
    v = wave_maxi(t);
  }
  return v;
}

// ---------------- stage kernels ----------------
__global__ void k_absmax_x(const float4* __restrict__ x, int n4, unsigned* slot) {
  float m = 0.f;
  for (int i = blockIdx.x * blockDim.x + threadIdx.x; i < n4; i += gridDim.x * blockDim.x) {
    float4 v = x[i];
    m = fmaxf(m, fmaxf(fmaxf(fabsf(v.x), fabsf(v.y)), fmaxf(fabsf(v.z), fabsf(v.w))));
  }
  m = block_maxf(m);
  if (!threadIdx.x) atomicMax(slot, __float_as_uint(m));
}

__global__ void k_absmax_w(const float* __restrict__ w1, const float* __restrict__ w2,
                           const float* __restrict__ wf1, const float* __restrict__ wf2,
                           Scal* sc) {
  const float* p; int n; unsigned* slot;
  if (blockIdx.x == 0)      { p = w1;  n = 864;   slot = &sc->max_w1; }
  else if (blockIdx.x == 1) { p = w2;  n = 18432; slot = &sc->max_w2; }
  else if (blockIdx.x == 2) { p = wf1; n = 8192;  slot = &sc->max_wf1; }
  else                      { p = wf2; n = 1280;  slot = &sc->max_wf2; }
  float m = 0.f;
  for (int i = threadIdx.x; i < n; i += blockDim.x) m = fmaxf(m, fabsf(p[i]));
  m = block_maxf(m);
  if (!threadIdx.x) atomicMax(slot, __float_as_uint(m));
}

__global__ void k_scales(Scal* sc) {
  sc->s_in = fmaxf(__uint_as_float(sc->max_x),  1e-8f) / 7.f;
  sc->sw1  = fmaxf(__uint_as_float(sc->max_w1), 1e-8f) / 7.f;
  sc->sw2  = fmaxf(__uint_as_float(sc->max_w2), 1e-8f) / 7.f;
  sc->swf1 = fmaxf(__uint_as_float(sc->max_wf1),1e-8f) / 7.f;
  sc->swf2 = fmaxf(__uint_as_float(sc->max_wf2),1e-8f) / 7.f;
}

// 4 floats -> 4 packed int8 codes per thread
__global__ void k_quant_x(const float4* __restrict__ x, unsigned* __restrict__ xq,
                          int n4, const Scal* __restrict__ sc) {
  float s = sc->s_in;
  int i = blockIdx.x * 256 + threadIdx.x;
  if (i >= n4) return;
  float4 v = x[i];
  float f[4] = {v.x, v.y, v.z, v.w};
  unsigned w = 0;
#pragma unroll
  for (int k = 0; k < 4; ++k) {
    float q = rintf(f[k] / s);
    q = fminf(fmaxf(q, -8.f), 7.f);
    w |= ((unsigned)((int)q & 255)) << (8 * k);
  }
  xq[i] = w;
}

// quantize w1 codes; pack w2 as [oc][kh][kw][ic] dwords (ic 4-per-dword); bias1 ints
__global__ void k_quant_w(const float* __restrict__ w1, const float* __restrict__ w2,
                          const float* __restrict__ b1, const Scal* __restrict__ sc,
                          signed char* __restrict__ qw1, unsigned* __restrict__ w2pk,
                          int* __restrict__ bint1) {
  int i = blockIdx.x * blockDim.x + threadIdx.x;
  if (i < 864) {
    float q = rintf(w1[i] / sc->sw1);
    q = fminf(fmaxf(q, -8.f), 7.f);
    qw1[i] = (signed char)(int)q;
  } else if (i < 864 + 4608) {
    int j = i - 864;           // output dword index
    int d = j & 7; int t = j >> 3;
    int kw = t % 3; t /= 3;
    int kh = t % 3; int oc = t / 3;
    float s = sc->sw2;
    unsigned w = 0;
#pragma unroll
    for (int k = 0; k < 4; ++k) {
      int ic = d * 4 + k;
      float q = rintf(w2[(oc * 32 + ic) * 9 + kh * 3 + kw] / s);
      q = fminf(fmaxf(q, -8.f), 7.f);
      w |= ((unsigned)((int)q & 255)) << (8 * k);
    }
    w2pk[j] = w;
  } else if (i < 864 + 4608 + 32) {
    int j = i - 5472;
    bint1[j] = (int)rintf(b1[j] / (sc->s_in * sc->sw1));
  }
}

// conv1 fused single pass: 3->32ch, 224^2 -> 222^2. 8 outputs/thread along ow.
// Stores raw int16 acc (padded row width 224, planar); block max of relu(acc).
__global__ void __launch_bounds__(256) k_conv1(
    const signed char* __restrict__ xq, const signed char* __restrict__ qw1,
    const int* __restrict__ bint1, short* __restrict__ y1acc, int* __restrict__ max1) {
  __shared__ signed char lw[864];
  int tid = threadIdx.x;
  if (tid < 216) ((int*)lw)[tid] = ((const int*)qw1)[tid];
  __syncthreads();

  int idx = blockIdx.x * 256 + tid;
  int g = idx % 28; int t = idx / 28;
  int oh = t % 222; t /= 222;
  int oc = t & 31, b = t >> 5;

  int w[9][3];
  {
    const signed char* wp = lw + oc * 27;
#pragma unroll
    for (int r = 0; r < 9; ++r)
#pragma unroll
      for (int k = 0; k < 3; ++k) w[r][k] = (int)wp[r * 3 + k];
  }
  int bias = bint1[oc];
  int acc[8];
#pragma unroll
  for (int j = 0; j < 8; ++j) acc[j] = bias;

  const signed char* xp = xq + ((b * 3) * 224 + oh) * 224 + g * 8;
#pragma unroll
  for (int ic = 0; ic < 3; ++ic) {
#pragma unroll
    for (int kh = 0; kh < 3; ++kh) {
      const signed char* xr = xp + (ic * 224 + kh) * 224;
      uint2 lo = *(const uint2*)xr;              // bytes 0..7   (8B aligned)
      unsigned hi = *(const unsigned*)(xr + 8);  // bytes 8..11  (4B aligned)
      int xv[10];
#pragma unroll
      for (int k = 0; k < 4; ++k) xv[k]     = (int)(signed char)(lo.x >> (8 * k));
#pragma unroll
      for (int k = 0; k < 4; ++k) xv[4 + k] = (int)(signed char)(lo.y >> (8 * k));
      xv[8] = (int)(signed char)(hi);
      xv[9] = (int)(signed char)(hi >> 8);
      int r = ic * 3 + kh;
      int w0 = w[r][0], w1 = w[r][1], w2 = w[r][2];
#pragma unroll
      for (int j = 0; j < 8; ++j)
        acc[j] += xv[j] * w0 + xv[j + 1] * w1 + xv[j + 2] * w2;
    }
  }

  size_t off = ((size_t)((b * 32 + oc) * 222 + oh)) * 224 + g * 8;
  uint4 st;
  st.x = ((unsigned)(unsigned short)acc[0]) | ((unsigned)(unsigned short)acc[1] << 16);
  st.y = ((unsigned)(unsigned short)acc[2]) | ((unsigned)(unsigned short)acc[3] << 16);
  st.z = ((unsigned)(unsigned short)acc[4]) | ((unsigned)(unsigned short)acc[5] << 16);
  st.w = ((unsigned)(unsigned short)acc[6]) | ((unsigned)(unsigned short)acc[7] << 16);
  *(uint4*)(y1acc + off) = st;

  int m = 0;
#pragma unroll
  for (int j = 0; j < 8; ++j) if (g * 8 + j < 222) m = max(m, acc[j]);
  m = block_maxi(m);
  if (!tid) atomicMax(max1, m);
}

__global__ void k_fin1(Scal* sc, const float* __restrict__ b2, int* __restrict__ bint2) {
  float sc1 = sc->s_in * sc->sw1;
  float s1 = fmaxf((float)sc->max1 * sc1, 1e-8f) / 15.f;
  if (!threadIdx.x) sc->s1 = s1;
  float sb = s1 * sc->sw2;
  bint2[threadIdx.x] = (int)rintf(b2[threadIdx.x] / sb);
}

// int16 planar acc -> NHWC uint8 relu4 codes (32 ic bytes contiguous per pixel)
__global__ void k_requant_t(const short* __restrict__ y1acc, const Scal* __restrict__ sc,
                            unsigned char* __restrict__ y1n) {
  int p = blockIdx.x * 256 + threadIdx.x;  // pixel within image (padded space)
  int b = blockIdx.y;
  if (p >= NPIX) return;
  float sc1 = sc->s_in * sc->sw1, s1 = sc->s1;
  const short* base = y1acc + (size_t)b * 32 * NPIX + p;
  unsigned w[8] = {0, 0, 0, 0, 0, 0, 0, 0};
#pragma unroll
  for (int oc = 0; oc < 32; ++oc) {
    int a = (int)base[(size_t)oc * NPIX];
    float y = (float)a * sc1;
    float q = rintf(y / s1);
    q = fminf(fmaxf(q, 0.f), 15.f);
    w[oc >> 2] |= ((unsigned)(int)q) << (8 * (oc & 3));
  }
  uint4* dst = (uint4*)(y1n + ((size_t)b * NPIX + p) * 32);
  dst[0] = make_uint4(w[0], w[1], w[2], w[3]);
  dst[1] = make_uint4(w[4], w[5], w[6], w[7]);
}

// conv2 via MFMA i8 implicit GEMM: one wave = 32 px (along ow) x 64 oc, K = 288.
// A-frag: A[m=lane&31][k=(lane>>5)*16+j] -> one coalesced 1024B wave load per tap.
// B-frag in LDS [tap][half][lane]*16B -> consecutive lanes, conflict-free b128.
// C/D: col=lane&31 (oc), row=(reg&3)+8*(reg>>2)+4*(lane>>5) (px).
__global__ void __launch_bounds__(256) k_conv2(
    const unsigned char* __restrict__ y1n, const unsigned* __restrict__ w2pk,
    const int* __restrict__ bint2, unsigned short* __restrict__ y2, int* __restrict__ max2) {
  __shared__ unsigned lw[4608];  // 18 KB: [(tap*2+half)*64 + dl]*4 + q
  int tid = threadIdx.x;
  for (int i = tid; i < 4608; i += 256) {
    int oc = i / 72, r = i - oc * 72;
    int tap = r >> 3, icq = r & 7;
    int dl = (oc & 31) | ((icq >> 2) << 5);
    lw[(((tap * 2) + (oc >> 5)) * 64 + dl) * 4 + (icq & 3)] = w2pk[i];
  }
  __syncthreads();

  int lane = tid & 63;
  int lane31 = lane & 31, lhalf = lane >> 5;
  int wv = blockIdx.x * 4 + (tid >> 6);      // global wave id
  int owg = wv % 7; int t = wv / 7;
  int oh = t % 220; int b = t / 220;
  int ow0 = owg * 32;

  int bias0 = bint2[lane31];
  int bias1 = bint2[32 + lane31];
  v16i acc0, acc1;
#pragma unroll
  for (int r = 0; r < 16; ++r) { acc0[r] = bias0; acc1[r] = bias1; }

  // per-lane A offset within a tap-row: px (lane&31), ic-bytes half (lane>>5)
  size_t aoff = (size_t)lane31 * 32 + (size_t)lhalf * 16;
#pragma unroll
  for (int kh = 0; kh < 3; ++kh) {
    const unsigned char* rowb = y1n + ((size_t)((b * 222 + oh + kh) * 224 + ow0)) * 32 + aoff;
#pragma unroll
    for (int kw = 0; kw < 3; ++kw) {
      int tap = kh * 3 + kw;
      v4i a = *(const v4i*)(rowb + kw * 32);
      v4i b0 = *(const v4i*)(lw + ((tap * 2 + 0) * 64 + lane) * 4);
      v4i b1 = *(const v4i*)(lw + ((tap * 2 + 1) * 64 + lane) * 4);
      acc0 = __builtin_amdgcn_mfma_i32_32x32x32_i8(a, b0, acc0, 0, 0, 0);
      acc1 = __builtin_amdgcn_mfma_i32_32x32x32_i8(a, b1, acc1, 0, 0, 0);
    }
  }

  size_t obase = (size_t)(b * 220 + oh) * 220;
  int mx = 0;
#pragma unroll
  for (int r = 0; r < 16; ++r) {
    int m = (r & 3) + 8 * (r >> 2) + 4 * lhalf;
    int ow = ow0 + m;
    if (ow < 220) {
      int a0 = acc0[r], a1 = acc1[r];
      unsigned short* dst = y2 + (obase + ow) * 64;
      dst[lane31]      = (unsigned short)min(max(a0, 0), 65535);
      dst[32 + lane31] = (unsigned short)min(max(a1, 0), 65535);
      mx = max(mx, max(a0, a1));
    }
  }
  mx = block_maxi(max(mx, 0));
  if (!tid) atomicMax(max2, mx);
}

__global__ void k_fin2(Scal* sc) {
  sc->s2 = fmaxf((float)sc->max2 * (sc->s1 * sc->sw2), 1e-8f) / 15.f;
}

// quantize y2 (NHWC) + global average pool: int sums accumulated per (b, oc)
__global__ void k_pool(const unsigned short* __restrict__ y2, const Scal* __restrict__ sc,
                       int* __restrict__ pooled_i) {
  int b = blockIdx.x;        // 0..31
  int chunk = blockIdx.y;    // 0..10 (4400 px each, 11*4400 = 48400)
  int oc = threadIdx.x & 63;
  int pr = threadIdx.x >> 6; // 0..3
  float sc2 = sc->s1 * sc->sw2, s2 = sc->s2;
  const unsigned short* base = y2 + ((size_t)b * 48400 + (size_t)chunk * 4400) * 64 + oc;
  int sum = 0;
  for (int i = pr; i < 4400; i += 4) {
    int a = (int)base[(size_t)i * 64];
    float y = (float)a * sc2;
    float q = rintf(y / s2);
    q = fminf(fmaxf(q, 0.f), 15.f);
    sum += (int)q;
  }
  __shared__ int red[4][64];
  red[pr][oc] = sum;
  __syncthreads();
  if (pr == 0) {
    int t = red[0][oc] + red[1][oc] + red[2][oc] + red[3][oc];
    atomicAdd(&pooled_i[b * 64 + oc], t);
  }
}

// whole FC head + log_softmax in one block
__global__ void k_fc(const int* __restrict__ pooled_i, const float* __restrict__ wf1,
                     const float* __restrict__ bf1, const float* __restrict__ wf2,
                     const float* __restrict__ bf2, const Scal* __restrict__ sc,
                     float* __restrict__ out) {
  __shared__ float pl[2048];
  __shared__ float wq1[8192];
  __shared__ float y3[4096];
  __shared__ float zz[320];
  __shared__ float s3sh;
  int tid = threadIdx.x;
  float swf1 = sc->swf1, swf2 = sc->swf2, s2 = sc->s2;
  for (int i = tid; i < 2048; i += 256) pl[i] = (float)pooled_i[i] * s2 / 48400.0f;
  for (int i = tid; i < 8192; i += 256) {
    float q = rintf(wf1[i] / swf1);
    q = fminf(fmaxf(q, -8.f), 7.f);
    wq1[i] = q * swf1;
  }
  __syncthreads();
  float sb1 = s2 * swf1;
  float lmax = 0.f;
  for (int o = tid; o < 4096; o += 256) {
    int b = o >> 7, j = o & 127;
    float acc = rintf(bf1[j] / sb1) * sb1;
    const float* wrow = &wq1[j * 64];
    const float* xrow = &pl[b * 64];
#pragma unroll 16
    for (int k = 0; k < 64; ++k) acc += xrow[k] * wrow[k];
    float r = fmaxf(acc, 0.f);
    y3[o] = r;
    lmax = fmaxf(lmax, r);
  }
  float m = block_maxf(lmax);  // contains a __syncthreads (after y3 writes)
  if (!tid) s3sh = fmaxf(m, 1e-8f) / 15.f;
  __syncthreads();
  float s3 = s3sh;
  float sb2 = s3 * swf2;
  for (int o = tid; o < 320; o += 256) {
    int b = o / 10, j = o - b * 10;
    float acc = rintf(bf2[j] / sb2) * sb2;
    const float* yy = &y3[b * 128];
    const float* wrow = &wf2[j * 128];
    for (int k = 0; k < 128; ++k) {
      float q = rintf(yy[k] / s3);
      q = fminf(fmaxf(q, 0.f), 15.f);
      float wv = rintf(wrow[k] / swf2);
      wv = fminf(fmaxf(wv, -8.f), 7.f);
      acc += (q * s3) * (wv * swf2);
    }
    zz[o] = acc;
  }
  __syncthreads();
  if (tid < 32) {
    const float* z = &zz[tid * 10];
    float mm = z[0];
    for (int k = 1; k < 10; ++k) mm = fmaxf(mm, z[k]);
    float ssum = 0.f;
    for (int k = 0; k < 10; ++k) ssum += expf(z[k] - mm);
    float l = mm + logf(ssum);
    for (int k = 0; k < 10; ++k) out[tid * 10 + k] = z[k] - l;
  }
}

extern "C" void kernel_launch(void* const* d_in, const int* in_sizes, int n_in,
                              void* d_out, int out_size, void* d_ws, size_t ws_size,
                              hipStream_t stream) {
  const float* x   = (const float*)d_in[0];
  const float* w1  = (const float*)d_in[1];
  const float* b1  = (const float*)d_in[2];
  const float* w2  = (const float*)d_in[3];
  const float* b2  = (const float*)d_in[4];
  const float* wf1 = (const float*)d_in[5];
  const float* bf1 = (const float*)d_in[6];
  const float* wf2 = (const float*)d_in[7];
  const float* bf2 = (const float*)d_in[8];
  float* out = (float*)d_out;

  char* ws = (char*)d_ws;
  Scal* sc = (Scal*)ws;
  size_t off = 1024;
  signed char* xq = (signed char*)(ws + off);   off += (size_t)NX + 256;  // +slack for edge reads
  off = (off + 255) & ~(size_t)255;
  signed char* qw1 = (signed char*)(ws + off);  off += 1024;
  unsigned* w2pk = (unsigned*)(ws + off);       off += 4608 * 4;          // [oc][kh][kw][ic/4]
  int* bint1 = (int*)(ws + off);                off += 256;
  int* bint2 = (int*)(ws + off);                off += 256;
  unsigned char* y1n = (unsigned char*)(ws + off); off += (size_t)NP1;    // NHWC codes
  off = (off + 255) & ~(size_t)255;
  int* pooled_i = (int*)(ws + off);             off += 8192;              // also slack for conv2 tail reads
  // y2 region (198 MB, NHWC u16) doubles as y1acc (102 MB) — y1acc fully consumed before conv2 writes y2
  unsigned short* y2 = (unsigned short*)(ws + off);
  short* y1acc = (short*)(ws + off);            off += (size_t)32 * 220 * 220 * 64 * 2;
  (void)ws_size; (void)in_sizes; (void)n_in; (void)out_size;

  hipMemsetAsync(sc, 0, 1024, stream);
  hipMemsetAsync(pooled_i, 0, 8192, stream);
  k_absmax_x<<<1024, 256, 0, stream>>>((const float4*)x, NX / 4, &sc->max_x);
  k_absmax_w<<<4, 256, 0, stream>>>(w1, w2, wf1, wf2, sc);
  k_scales<<<1, 1, 0, stream>>>(sc);
  k_quant_x<<<NX / 4 / 256, 256, 0, stream>>>((const float4*)x, (unsigned*)xq, NX / 4, sc);
  k_quant_w<<<22, 256, 0, stream>>>(w1, w2, b1, sc, qw1, w2pk, bint1);
  k_conv1<<<NCONV1 / 256, 256, 0, stream>>>(xq, qw1, bint1, y1acc, &sc->max1);
  k_fin1<<<1, 64, 0, stream>>>(sc, b2, bint2);
  k_requant_t<<<dim3(195, 32), 256, 0, stream>>>(y1acc, sc, y1n);
  k_conv2<<<NW2 / 4, 256, 0, stream>>>(y1n, w2pk, bint2, y2, &sc->max2);
  k_fin2<<<1, 1, 0, stream>>>(sc);
  k_pool<<<dim3(32, 11), 256, 0, stream>>>(y2, sc, pooled_i);
  k_fc<<<1, 256, 0, stream>>>(pooled_i, wf1, bf1, wf2, bf2, sc, out);
}

// Round 6
// 901.882 us; speedup vs baseline: 2.5637x; 1.0018x over previous
//
#include <hip/hip_runtime.h>
#include <cstdint>
#include <cstddef>

#define DI __device__ __forceinline__

typedef int v4i  __attribute__((ext_vector_type(4)));
typedef int v16i __attribute__((ext_vector_type(16)));

#if defined(__has_builtin)
#if __has_builtin(__builtin_amdgcn_sdot4)
#define HAS_SDOT4 1
#endif
#if __has_builtin(__builtin_amdgcn_alignbyte)
#define HAS_ALIGNBYTE 1
#endif
#endif

DI int dot4(unsigned a, unsigned b, int c) {
#ifdef HAS_SDOT4
  return __builtin_amdgcn_sdot4((int)a, (int)b, c, false);
#else
#pragma unroll
  for (int k = 0; k < 4; ++k)
    c += (int)(signed char)(a >> (8 * k)) * (int)(signed char)(b >> (8 * k));
  return c;
#endif
}

DI unsigned alignb(unsigned hi, unsigned lo, int sh) {  // bytes (hi:lo) >> 8*sh
#ifdef HAS_ALIGNBYTE
  return __builtin_amdgcn_alignbyte(hi, lo, sh);
#else
  return (lo >> (8 * sh)) | (hi << (32 - 8 * sh));
#endif
}

// ---------------- scalar block in workspace ----------------
struct Scal {
  unsigned max_x, max_w1, max_w2, max_wf1, max_wf2;  // float bits (abs-max, >=0)
  float s_in, sw1, sw2, swf1, swf2;
  int   max1; float s1;
  int   max2; float s2;
};

static constexpr int NX   = 32 * 3 * 224 * 224;     // 4,816,896
static constexpr int NP1  = 32 * 32 * 222 * 224;    // 50,921,472 padded conv1 outputs
static constexpr int NPIX = 222 * 224;              // 49,728 padded pixels per image
static constexpr int NCONV1 = 32 * 32 * 222 * 28;   // 6,365,184 threads (8 outputs each)
static constexpr int NW2 = 32 * 220 * 7;            // conv2 waves: 32 px x 64 oc tiles

// ---------------- reduction helpers (blockDim == 256) ----------------
DI float wave_maxf(float v) { for (int o = 32; o; o >>= 1) v = fmaxf(v, __shfl_down(v, o, 64)); return v; }
DI int   wave_maxi(int v)   { for (int o = 32; o; o >>= 1) v = max(v, __shfl_down(v, o, 64));   return v; }

DI float block_maxf(float v) {  // valid in thread 0; all values >= 0
  __shared__ float s[4];
  v = wave_maxf(v);
  int lane = threadIdx.x & 63, w = threadIdx.x >> 6;
  if (!lane) s[w] = v;
  __syncthreads();
  if (threadIdx.x < 64) {
    float t = (threadIdx.x < 4) ? s[threadIdx.x] : 0.f;
    v = wave_maxf(t);
  }
  return v;
}

DI int block_maxi(int v) {  // valid in thread 0; all values >= 0
  __shared__ int s[4];
  v = wave_maxi(v);
  int lane = threadIdx.x & 63, w = threadIdx.x >> 6;
  if (!lane) s[w] = v;
  __syncthreads();
  if (threadIdx.x < 64) {
    int t = (threadIdx.x < 4) ? s[threadIdx.x] : 0;
    v = wave_maxi(t);
  }
  return v;
}

// ---------------- stage kernels ----------------
__global__ void k_absmax_x(const float4* __restrict__ x, int n4, unsigned* slot) {
  float m = 0.f;
  for (int i = blockIdx.x * blockDim.x + threadIdx.x; i < n4; i += gridDim.x * blockDim.x) {
    float4 v = x[i];
    m = fmaxf(m, fmaxf(fmaxf(fabsf(v.x), fabsf(v.y)), fmaxf(fabsf(v.z), fabsf(v.w))));
  }
  m = block_maxf(m);
  if (!threadIdx.x) atomicMax(slot, __float_as_uint(m));
}

__global__ void k_absmax_w(const float* __restrict__ w1, const float* __restrict__ w2,
                           const float* __restrict__ wf1, const float* __restrict__ wf2,
                           Scal* sc) {
  const float* p; int n; unsigned* slot;
  if (blockIdx.x == 0)      { p = w1;  n = 864;   slot = &sc->max_w1; }
  else if (blockIdx.x == 1) { p = w2;  n = 18432; slot = &sc->max_w2; }
  else if (blockIdx.x == 2) { p = wf1; n = 8192;  slot = &sc->max_wf1; }
  else                      { p = wf2; n = 1280;  slot = &sc->max_wf2; }
  float m = 0.f;
  for (int i = threadIdx.x; i < n; i += blockDim.x) m = fmaxf(m, fabsf(p[i]));
  m = block_maxf(m);
  if (!threadIdx.x) atomicMax(slot, __float_as_uint(m));
}

__global__ void k_scales(Scal* sc) {
  sc->s_in = fmaxf(__uint_as_float(sc->max_x),  1e-8f) / 7.f;
  sc->sw1  = fmaxf(__uint_as_float(sc->max_w1), 1e-8f) / 7.f;
  sc->sw2  = fmaxf(__uint_as_float(sc->max_w2), 1e-8f) / 7.f;
  sc->swf1 = fmaxf(__uint_as_float(sc->max_wf1),1e-8f) / 7.f;
  sc->swf2 = fmaxf(__uint_as_float(sc->max_wf2),1e-8f) / 7.f;
}

// 4 floats -> 4 packed int8 codes per thread
__global__ void k_quant_x(const float4* __restrict__ x, unsigned* __restrict__ xq,
                          int n4, const Scal* __restrict__ sc) {
  float s = sc->s_in;
  int i = blockIdx.x * 256 + threadIdx.x;
  if (i >= n4) return;
  float4 v = x[i];
  float f[4] = {v.x, v.y, v.z, v.w};
  unsigned w = 0;
#pragma unroll
  for (int k = 0; k < 4; ++k) {
    float q = rintf(f[k] / s);
    q = fminf(fmaxf(q, -8.f), 7.f);
    w |= ((unsigned)((int)q & 255)) << (8 * k);
  }
  xq[i] = w;
}

// pack w1 as [oc][row] dwords {w0,w1,w2,0}; w2 as [oc][kh][kw][ic/4] dwords; bias1 ints
__global__ void k_quant_w(const float* __restrict__ w1, const float* __restrict__ w2,
                          const float* __restrict__ b1, const Scal* __restrict__ sc,
                          unsigned* __restrict__ w1pk, unsigned* __restrict__ w2pk,
                          int* __restrict__ bint1) {
  int i = blockIdx.x * blockDim.x + threadIdx.x;
  if (i < 288) {
    int oc = i / 9, r = i - oc * 9;   // r = ic*3 + kh; bytes = kw 0..2
    float s = sc->sw1;
    unsigned w = 0;
#pragma unroll
    for (int k = 0; k < 3; ++k) {
      float q = rintf(w1[oc * 27 + r * 3 + k] / s);
      q = fminf(fmaxf(q, -8.f), 7.f);
      w |= ((unsigned)((int)q & 255)) << (8 * k);
    }
    w1pk[i] = w;
  } else if (i < 288 + 4608) {
    int j = i - 288;           // output dword index
    int d = j & 7; int t = j >> 3;
    int kw = t % 3; t /= 3;
    int kh = t % 3; int oc = t / 3;
    float s = sc->sw2;
    unsigned w = 0;
#pragma unroll
    for (int k = 0; k < 4; ++k) {
      int ic = d * 4 + k;
      float q = rintf(w2[(oc * 32 + ic) * 9 + kh * 3 + kw] / s);
      q = fminf(fmaxf(q, -8.f), 7.f);
      w |= ((unsigned)((int)q & 255)) << (8 * k);
    }
    w2pk[j] = w;
  } else if (i < 288 + 4608 + 32) {
    int j = i - 4896;
    bint1[j] = (int)rintf(b1[j] / (sc->s_in * sc->sw1));
  }
}

// conv1 fused single pass: 3->32ch, 224^2 -> 222^2. 8 outputs/thread along ow.
// All 27 input dwords loaded upfront (one in-flight batch); per row one packed
// weight dword {w0,w1,w2,0} and 8 sliding windows via alignbyte + sdot4.
// Stores raw int16 acc (padded row width 224, planar); block max of relu(acc).
__global__ void __launch_bounds__(256) k_conv1(
    const signed char* __restrict__ xq, const unsigned* __restrict__ w1pk,
    const int* __restrict__ bint1, short* __restrict__ y1acc, int* __restrict__ max1) {
  __shared__ unsigned lw[288];
  int tid = threadIdx.x;
  for (int i = tid; i < 288; i += 256) lw[i] = w1pk[i];
  __syncthreads();

  int idx = blockIdx.x * 256 + tid;
  int g = idx % 28; int t = idx / 28;
  int oh = t % 222; t /= 222;
  int oc = t & 31, b = t >> 5;

  // load all 9 row segments (12B each) upfront
  const signed char* xp = xq + ((b * 3) * 224 + oh) * 224 + g * 8;
  unsigned d0[9], d1[9], d2[9];
#pragma unroll
  for (int r = 0; r < 9; ++r) {
    int ic = r / 3, kh = r - ic * 3;
    const signed char* xr = xp + (ic * 224 + kh) * 224;
    uint2 lo = *(const uint2*)xr;              // 8B aligned
    d0[r] = lo.x; d1[r] = lo.y;
    d2[r] = *(const unsigned*)(xr + 8);        // 4B aligned
  }
  unsigned w[9];
#pragma unroll
  for (int r = 0; r < 9; ++r) w[r] = lw[oc * 9 + r];

  int bias = bint1[oc];
  int acc[8];
#pragma unroll
  for (int j = 0; j < 8; ++j) acc[j] = bias;

#pragma unroll
  for (int r = 0; r < 9; ++r) {
    unsigned wr = w[r];
    acc[0] = dot4(d0[r], wr, acc[0]);
    acc[1] = dot4(alignb(d1[r], d0[r], 1), wr, acc[1]);
    acc[2] = dot4(alignb(d1[r], d0[r], 2), wr, acc[2]);
    acc[3] = dot4(alignb(d1[r], d0[r], 3), wr, acc[3]);
    acc[4] = dot4(d1[r], wr, acc[4]);
    acc[5] = dot4(alignb(d2[r], d1[r], 1), wr, acc[5]);
    acc[6] = dot4(alignb(d2[r], d1[r], 2), wr, acc[6]);
    acc[7] = dot4(alignb(d2[r], d1[r], 3), wr, acc[7]);
  }

  size_t off = ((size_t)((b * 32 + oc) * 222 + oh)) * 224 + g * 8;
  uint4 st;
  st.x = ((unsigned)(unsigned short)acc[0]) | ((unsigned)(unsigned short)acc[1] << 16);
  st.y = ((unsigned)(unsigned short)acc[2]) | ((unsigned)(unsigned short)acc[3] << 16);
  st.z = ((unsigned)(unsigned short)acc[4]) | ((unsigned)(unsigned short)acc[5] << 16);
  st.w = ((unsigned)(unsigned short)acc[6]) | ((unsigned)(unsigned short)acc[7] << 16);
  *(uint4*)(y1acc + off) = st;

  int m = 0;
#pragma unroll
  for (int j = 0; j < 8; ++j) if (g * 8 + j < 222) m = max(m, acc[j]);
  m = block_maxi(m);
  if (!tid) atomicMax(max1, m);
}

__global__ void k_fin1(Scal* sc, const float* __restrict__ b2, int* __restrict__ bint2) {
  float sc1 = sc->s_in * sc->sw1;
  float s1 = fmaxf((float)sc->max1 * sc1, 1e-8f) / 15.f;
  if (!threadIdx.x) sc->s1 = s1;
  float sb = s1 * sc->sw2;
  bint2[threadIdx.x] = (int)rintf(b2[threadIdx.x] / sb);
}

// int16 planar acc -> NHWC uint8 relu4 codes (32 ic bytes contiguous per pixel)
__global__ void k_requant_t(const short* __restrict__ y1acc, const Scal* __restrict__ sc,
                            unsigned char* __restrict__ y1n) {
  int p = blockIdx.x * 256 + threadIdx.x;  // pixel within image (padded space)
  int b = blockIdx.y;
  if (p >= NPIX) return;
  float sc1 = sc->s_in * sc->sw1, s1 = sc->s1;
  const short* base = y1acc + (size_t)b * 32 * NPIX + p;
  unsigned w[8] = {0, 0, 0, 0, 0, 0, 0, 0};
#pragma unroll
  for (int oc = 0; oc < 32; ++oc) {
    int a = (int)base[(size_t)oc * NPIX];
    float y = (float)a * sc1;
    float q = rintf(y / s1);
    q = fminf(fmaxf(q, 0.f), 15.f);
    w[oc >> 2] |= ((unsigned)(int)q) << (8 * (oc & 3));
  }
  uint4* dst = (uint4*)(y1n + ((size_t)b * NPIX + p) * 32);
  dst[0] = make_uint4(w[0], w[1], w[2], w[3]);
  dst[1] = make_uint4(w[4], w[5], w[6], w[7]);
}

// conv2 via MFMA i8 implicit GEMM: one wave = 32 px (along ow) x 64 oc, K = 288.
__global__ void __launch_bounds__(256) k_conv2(
    const unsigned char* __restrict__ y1n, const unsigned* __restrict__ w2pk,
    const int* __restrict__ bint2, unsigned short* __restrict__ y2, int* __restrict__ max2) {
  __shared__ unsigned lw[4608];  // 18 KB: [(tap*2+half)*64 + dl]*4 + q
  int tid = threadIdx.x;
  for (int i = tid; i < 4608; i += 256) {
    int oc = i / 72, r = i - oc * 72;
    int tap = r >> 3, icq = r & 7;
    int dl = (oc & 31) | ((icq >> 2) << 5);
    lw[(((tap * 2) + (oc >> 5)) * 64 + dl) * 4 + (icq & 3)] = w2pk[i];
  }
  __syncthreads();

  int lane = tid & 63;
  int lane31 = lane & 31, lhalf = lane >> 5;
  int wv = blockIdx.x * 4 + (tid >> 6);      // global wave id
  int owg = wv % 7; int t = wv / 7;
  int oh = t % 220; int b = t / 220;
  int ow0 = owg * 32;

  int bias0 = bint2[lane31];
  int bias1 = bint2[32 + lane31];
  v16i acc0, acc1;
#pragma unroll
  for (int r = 0; r < 16; ++r) { acc0[r] = bias0; acc1[r] = bias1; }

  size_t aoff = (size_t)lane31 * 32 + (size_t)lhalf * 16;
#pragma unroll
  for (int kh = 0; kh < 3; ++kh) {
    const unsigned char* rowb = y1n + ((size_t)((b * 222 + oh + kh) * 224 + ow0)) * 32 + aoff;
#pragma unroll
    for (int kw = 0; kw < 3; ++kw) {
      int tap = kh * 3 + kw;
      v4i a = *(const v4i*)(rowb + kw * 32);
      v4i b0 = *(const v4i*)(lw + ((tap * 2 + 0) * 64 + lane) * 4);
      v4i b1 = *(const v4i*)(lw + ((tap * 2 + 1) * 64 + lane) * 4);
      acc0 = __builtin_amdgcn_mfma_i32_32x32x32_i8(a, b0, acc0, 0, 0, 0);
      acc1 = __builtin_amdgcn_mfma_i32_32x32x32_i8(a, b1, acc1, 0, 0, 0);
    }
  }

  size_t obase = (size_t)(b * 220 + oh) * 220;
  int mx = 0;
#pragma unroll
  for (int r = 0; r < 16; ++r) {
    int m = (r & 3) + 8 * (r >> 2) + 4 * lhalf;
    int ow = ow0 + m;
    if (ow < 220) {
      int a0 = acc0[r], a1 = acc1[r];
      unsigned short* dst = y2 + (obase + ow) * 64;
      dst[lane31]      = (unsigned short)min(max(a0, 0), 65535);
      dst[32 + lane31] = (unsigned short)min(max(a1, 0), 65535);
      mx = max(mx, max(a0, a1));
    }
  }
  mx = block_maxi(max(mx, 0));
  if (!tid) atomicMax(max2, mx);
}

__global__ void k_fin2(Scal* sc) {
  sc->s2 = fmaxf((float)sc->max2 * (sc->s1 * sc->sw2), 1e-8f) / 15.f;
}

// quantize y2 (NHWC) + global average pool: int sums accumulated per (b, oc)
__global__ void k_pool(const unsigned short* __restrict__ y2, const Scal* __restrict__ sc,
                       int* __restrict__ pooled_i) {
  int b = blockIdx.x;        // 0..31
  int chunk = blockIdx.y;    // 0..10 (4400 px each, 11*4400 = 48400)
  int oc = threadIdx.x & 63;
  int pr = threadIdx.x >> 6; // 0..3
  float sc2 = sc->s1 * sc->sw2, s2 = sc->s2;
  const unsigned short* base = y2 + ((size_t)b * 48400 + (size_t)chunk * 4400) * 64 + oc;
  int sum = 0;
  for (int i = pr; i < 4400; i += 4) {
    int a = (int)base[(size_t)i * 64];
    float y = (float)a * sc2;
    float q = rintf(y / s2);
    q = fminf(fmaxf(q, 0.f), 15.f);
    sum += (int)q;
  }
  __shared__ int red[4][64];
  red[pr][oc] = sum;
  __syncthreads();
  if (pr == 0) {
    int t = red[0][oc] + red[1][oc] + red[2][oc] + red[3][oc];
    atomicAdd(&pooled_i[b * 64 + oc], t);
  }
}

// whole FC head + log_softmax in one block
__global__ void k_fc(const int* __restrict__ pooled_i, const float* __restrict__ wf1,
                     const float* __restrict__ bf1, const float* __restrict__ wf2,
                     const float* __restrict__ bf2, const Scal* __restrict__ sc,
                     float* __restrict__ out) {
  __shared__ float pl[2048];
  __shared__ float wq1[8192];
  __shared__ float y3[4096];
  __shared__ float zz[320];
  __shared__ float s3sh;
  int tid = threadIdx.x;
  float swf1 = sc->swf1, swf2 = sc->swf2, s2 = sc->s2;
  for (int i = tid; i < 2048; i += 256) pl[i] = (float)pooled_i[i] * s2 / 48400.0f;
  for (int i = tid; i < 8192; i += 256) {
    float q = rintf(wf1[i] / swf1);
    q = fminf(fmaxf(q, -8.f), 7.f);
    wq1[i] = q * swf1;
  }
  __syncthreads();
  float sb1 = s2 * swf1;
  float lmax = 0.f;
  for (int o = tid; o < 4096; o += 256) {
    int b = o >> 7, j = o & 127;
    float acc = rintf(bf1[j] / sb1) * sb1;
    const float* wrow = &wq1[j * 64];
    const float* xrow = &pl[b * 64];
#pragma unroll 16
    for (int k = 0; k < 64; ++k) acc += xrow[k] * wrow[k];
    float r = fmaxf(acc, 0.f);
    y3[o] = r;
    lmax = fmaxf(lmax, r);
  }
  float m = block_maxf(lmax);  // contains a __syncthreads (after y3 writes)
  if (!tid) s3sh = fmaxf(m, 1e-8f) / 15.f;
  __syncthreads();
  float s3 = s3sh;
  float sb2 = s3 * swf2;
  for (int o = tid; o < 320; o += 256) {
    int b = o / 10, j = o - b * 10;
    float acc = rintf(bf2[j] / sb2) * sb2;
    const float* yy = &y3[b * 128];
    const float* wrow = &wf2[j * 128];
    for (int k = 0; k < 128; ++k) {
      float q = rintf(yy[k] / s3);
      q = fminf(fmaxf(q, 0.f), 15.f);
      float wv = rintf(wrow[k] / swf2);
      wv = fminf(fmaxf(wv, -8.f), 7.f);
      acc += (q * s3) * (wv * swf2);
    }
    zz[o] = acc;
  }
  __syncthreads();
  if (tid < 32) {
    const float* z = &zz[tid * 10];
    float mm = z[0];
    for (int k = 1; k < 10; ++k) mm = fmaxf(mm, z[k]);
    float ssum = 0.f;
    for (int k = 0; k < 10; ++k) ssum += expf(z[k] - mm);
    float l = mm + logf(ssum);
    for (int k = 0; k < 10; ++k) out[tid * 10 + k] = z[k] - l;
  }
}

extern "C" void kernel_launch(void* const* d_in, const int* in_sizes, int n_in,
                              void* d_out, int out_size, void* d_ws, size_t ws_size,
                              hipStream_t stream) {
  const float* x   = (const float*)d_in[0];
  const float* w1  = (const float*)d_in[1];
  const float* b1  = (const float*)d_in[2];
  const float* w2  = (const float*)d_in[3];
  const float* b2  = (const float*)d_in[4];
  const float* wf1 = (const float*)d_in[5];
  const float* bf1 = (const float*)d_in[6];
  const float* wf2 = (const float*)d_in[7];
  const float* bf2 = (const float*)d_in[8];
  float* out = (float*)d_out;

  char* ws = (char*)d_ws;
  Scal* sc = (Scal*)ws;
  size_t off = 1024;
  signed char* xq = (signed char*)(ws + off);   off += (size_t)NX + 256;  // +slack for edge reads
  off = (off + 255) & ~(size_t)255;
  unsigned* w1pk = (unsigned*)(ws + off);       off += 2048;              // [oc][row] {w0,w1,w2,0}
  unsigned* w2pk = (unsigned*)(ws + off);       off += 4608 * 4;          // [oc][kh][kw][ic/4]
  int* bint1 = (int*)(ws + off);                off += 256;
  int* bint2 = (int*)(ws + off);                off += 256;
  unsigned char* y1n = (unsigned char*)(ws + off); off += (size_t)NP1;    // NHWC codes
  off = (off + 255) & ~(size_t)255;
  int* pooled_i = (int*)(ws + off);             off += 8192;              // also slack for conv2 tail reads
  // y2 region (198 MB, NHWC u16) doubles as y1acc (102 MB) — y1acc fully consumed before conv2 writes y2
  unsigned short* y2 = (unsigned short*)(ws + off);
  short* y1acc = (short*)(ws + off);            off += (size_t)32 * 220 * 220 * 64 * 2;
  (void)ws_size; (void)in_sizes; (void)n_in; (void)out_size;

  hipMemsetAsync(sc, 0, 1024, stream);
  hipMemsetAsync(pooled_i, 0, 8192, stream);
  k_absmax_x<<<1024, 256, 0, stream>>>((const float4*)x, NX / 4, &sc->max_x);
  k_absmax_w<<<4, 256, 0, stream>>>(w1, w2, wf1, wf2, sc);
  k_scales<<<1, 1, 0, stream>>>(sc);
  k_quant_x<<<NX / 4 / 256, 256, 0, stream>>>((const float4*)x, (unsigned*)xq, NX / 4, sc);
  k_quant_w<<<22, 256, 0, stream>>>(w1, w2, b1, sc, w1pk, w2pk, bint1);
  k_conv1<<<NCONV1 / 256, 256, 0, stream>>>(xq, w1pk, bint1, y1acc, &sc->max1);
  k_fin1<<<1, 64, 0, stream>>>(sc, b2, bint2);
  k_requant_t<<<dim3(195, 32), 256, 0, stream>>>(y1acc, sc, y1n);
  k_conv2<<<NW2 / 4, 256, 0, stream>>>(y1n, w2pk, bint2, y2, &sc->max2);
  k_fin2<<<1, 1, 0, stream>>>(sc);
  k_pool<<<dim3(32, 11), 256, 0, stream>>>(y2, sc, pooled_i);
  k_fc<<<1, 256, 0, stream>>>(pooled_i, wf1, bf1, wf2, bf2, sc, out);
}

// Round 7
// 656.889 us; speedup vs baseline: 3.5198x; 1.3730x over previous
//
#include <hip/hip_runtime.h>
#include <cstdint>
#include <cstddef>

#define DI __device__ __forceinline__

typedef int v4i  __attribute__((ext_vector_type(4)));
typedef int v16i __attribute__((ext_vector_type(16)));

#if defined(__has_builtin)
#if __has_builtin(__builtin_amdgcn_sdot4)
#define HAS_SDOT4 1
#endif
#if __has_builtin(__builtin_amdgcn_alignbyte)
#define HAS_ALIGNBYTE 1
#endif
#endif

DI int dot4(unsigned a, unsigned b, int c) {
#ifdef HAS_SDOT4
  return __builtin_amdgcn_sdot4((int)a, (int)b, c, false);
#else
#pragma unroll
  for (int k = 0; k < 4; ++k)
    c += (int)(signed char)(a >> (8 * k)) * (int)(signed char)(b >> (8 * k));
  return c;
#endif
}

DI unsigned alignb(unsigned hi, unsigned lo, int sh) {  // bytes (hi:lo) >> 8*sh
#ifdef HAS_ALIGNBYTE
  return __builtin_amdgcn_alignbyte(hi, lo, sh);
#else
  return (lo >> (8 * sh)) | (hi << (32 - 8 * sh));
#endif
}

// ---------------- scalar block in workspace ----------------
struct Scal {
  unsigned max_x, max_w1, max_w2, max_wf1, max_wf2;  // float bits (abs-max, >=0)
  float s_in, sw1, sw2, swf1, swf2;
  int   max1; float s1;
  int   max2; float s2;
};

static constexpr int NX   = 32 * 3 * 224 * 224;     // 4,816,896
static constexpr int NP1  = 32 * 32 * 222 * 224;    // 50,921,472 padded conv1 outputs
static constexpr int NPIX = 222 * 224;              // 49,728 padded pixels per image
static constexpr int NW2 = 32 * 220 * 7;            // conv2 waves: 32 px x 64 oc tiles

// ---------------- reduction helpers (blockDim == 256) ----------------
DI float wave_maxf(float v) { for (int o = 32; o; o >>= 1) v = fmaxf(v, __shfl_down(v, o, 64)); return v; }
DI int   wave_maxi(int v)   { for (int o = 32; o; o >>= 1) v = max(v, __shfl_down(v, o, 64));   return v; }

DI float block_maxf(float v) {  // valid in thread 0; all values >= 0
  __shared__ float s[4];
  v = wave_maxf(v);
  int lane = threadIdx.x & 63, w = threadIdx.x >> 6;
  if (!lane) s[w] = v;
  __syncthreads();
  if (threadIdx.x < 64) {
    float t = (threadIdx.x < 4) ? s[threadIdx.x] : 0.f;
    v = wave_maxf(t);
  }
  return v;
}

DI int block_maxi(int v) {  // valid in thread 0; all values >= 0
  __shared__ int s[4];
  v = wave_maxi(v);
  int lane = threadIdx.x & 63, w = threadIdx.x >> 6;
  if (!lane) s[w] = v;
  __syncthreads();
  if (threadIdx.x < 64) {
    int t = (threadIdx.x < 4) ? s[threadIdx.x] : 0;
    v = wave_maxi(t);
  }
  return v;
}

// ---------------- stage kernels ----------------
__global__ void k_absmax_x(const float4* __restrict__ x, int n4, unsigned* slot) {
  float m = 0.f;
  for (int i = blockIdx.x * blockDim.x + threadIdx.x; i < n4; i += gridDim.x * blockDim.x) {
    float4 v = x[i];
    m = fmaxf(m, fmaxf(fmaxf(fabsf(v.x), fabsf(v.y)), fmaxf(fabsf(v.z), fabsf(v.w))));
  }
  m = block_maxf(m);
  if (!threadIdx.x) atomicMax(slot, __float_as_uint(m));
}

__global__ void k_absmax_w(const float* __restrict__ w1, const float* __restrict__ w2,
                           const float* __restrict__ wf1, const float* __restrict__ wf2,
                           Scal* sc) {
  const float* p; int n; unsigned* slot;
  if (blockIdx.x == 0)      { p = w1;  n = 864;   slot = &sc->max_w1; }
  else if (blockIdx.x == 1) { p = w2;  n = 18432; slot = &sc->max_w2; }
  else if (blockIdx.x == 2) { p = wf1; n = 8192;  slot = &sc->max_wf1; }
  else                      { p = wf2; n = 1280;  slot = &sc->max_wf2; }
  float m = 0.f;
  for (int i = threadIdx.x; i < n; i += blockDim.x) m = fmaxf(m, fabsf(p[i]));
  m = block_maxf(m);
  if (!threadIdx.x) atomicMax(slot, __float_as_uint(m));
}

__global__ void k_scales(Scal* sc) {
  sc->s_in = fmaxf(__uint_as_float(sc->max_x),  1e-8f) / 7.f;
  sc->sw1  = fmaxf(__uint_as_float(sc->max_w1), 1e-8f) / 7.f;
  sc->sw2  = fmaxf(__uint_as_float(sc->max_w2), 1e-8f) / 7.f;
  sc->swf1 = fmaxf(__uint_as_float(sc->max_wf1),1e-8f) / 7.f;
  sc->swf2 = fmaxf(__uint_as_float(sc->max_wf2),1e-8f) / 7.f;
}

// 4 floats -> 4 packed int8 codes per thread
__global__ void k_quant_x(const float4* __restrict__ x, unsigned* __restrict__ xq,
                          int n4, const Scal* __restrict__ sc) {
  float s = sc->s_in;
  int i = blockIdx.x * 256 + threadIdx.x;
  if (i >= n4) return;
  float4 v = x[i];
  float f[4] = {v.x, v.y, v.z, v.w};
  unsigned w = 0;
#pragma unroll
  for (int k = 0; k < 4; ++k) {
    float q = rintf(f[k] / s);
    q = fminf(fmaxf(q, -8.f), 7.f);
    w |= ((unsigned)((int)q & 255)) << (8 * k);
  }
  xq[i] = w;
}

// pack w1 as [oc][row] dwords {w0,w1,w2,0}; w2 as [oc][kh][kw][ic/4] dwords; bias1 ints
__global__ void k_quant_w(const float* __restrict__ w1, const float* __restrict__ w2,
                          const float* __restrict__ b1, const Scal* __restrict__ sc,
                          unsigned* __restrict__ w1pk, unsigned* __restrict__ w2pk,
                          int* __restrict__ bint1) {
  int i = blockIdx.x * blockDim.x + threadIdx.x;
  if (i < 288) {
    int oc = i / 9, r = i - oc * 9;   // r = ic*3 + kh; bytes = kw 0..2
    float s = sc->sw1;
    unsigned w = 0;
#pragma unroll
    for (int k = 0; k < 3; ++k) {
      float q = rintf(w1[oc * 27 + r * 3 + k] / s);
      q = fminf(fmaxf(q, -8.f), 7.f);
      w |= ((unsigned)((int)q & 255)) << (8 * k);
    }
    w1pk[i] = w;
  } else if (i < 288 + 4608) {
    int j = i - 288;           // output dword index
    int d = j & 7; int t = j >> 3;
    int kw = t % 3; t /= 3;
    int kh = t % 3; int oc = t / 3;
    float s = sc->sw2;
    unsigned w = 0;
#pragma unroll
    for (int k = 0; k < 4; ++k) {
      int ic = d * 4 + k;
      float q = rintf(w2[(oc * 32 + ic) * 9 + kh * 3 + kw] / s);
      q = fminf(fmaxf(q, -8.f), 7.f);
      w |= ((unsigned)((int)q & 255)) << (8 * k);
    }
    w2pk[j] = w;
  } else if (i < 288 + 4608 + 32) {
    int j = i - 4896;
    bint1[j] = (int)rintf(b1[j] / (sc->s_in * sc->sw1));
  }
}

// conv1 LDS-tiled: one block = (b, strip of 6 oh rows). Stage 3 ic x 8 input
// rows (5.3 KB) + weights + bias in LDS once; 256 threads sweep 28 g x 6 oh x
// 32 oc tasks (21 iters) with sdot4+alignbyte on LDS segments. Stores planar
// int16 acc; block max of relu(acc) over valid cols.
__global__ void __launch_bounds__(256) k_conv1(
    const signed char* __restrict__ xq, const unsigned* __restrict__ w1pk,
    const int* __restrict__ bint1, short* __restrict__ y1acc, int* __restrict__ max1) {
  __shared__ signed char lx[3 * 8 * 224 + 16];  // [ic][row 0..7][224] + pad
  __shared__ unsigned lw[288];
  __shared__ int lb[32];
  int tid = threadIdx.x;
  int strip = blockIdx.x;   // 0..36 (222 = 6*37)
  int b = blockIdx.y;       // 0..31
  int oh0 = strip * 6;

  for (int i = tid; i < 288; i += 256) lw[i] = w1pk[i];
  if (tid < 32) lb[tid] = bint1[tid];
  {
    const unsigned* src = (const unsigned*)(xq + (size_t)b * 3 * 224 * 224);
    unsigned* dst = (unsigned*)lx;
    // 24 rows x 56 dwords = 1344 dwords, coalesced
#pragma unroll
    for (int it = 0; it < 6; ++it) {
      int i = it * 256 + tid;
      if (i < 1344) {
        int row = i / 56, d = i - row * 56;   // row = ic*8 + r
        int ic = row >> 3, r = row & 7;
        dst[i] = src[(ic * 224 + (oh0 + r)) * 56 + d];
      }
    }
  }
  __syncthreads();

  int mx = 0;
  for (int it = 0; it < 21; ++it) {
    int i = it * 256 + tid;          // 5376 tasks: g fast, then oh_l, then oc
    int g = i % 28;
    int r = i / 28;
    int oh_l = r % 6;
    int oc = r / 6;

    int bias = lb[oc];
    int acc[8];
#pragma unroll
    for (int j = 0; j < 8; ++j) acc[j] = bias;

#pragma unroll
    for (int seg = 0; seg < 9; ++seg) {
      int ic = seg / 3, kh = seg - ic * 3;
      const signed char* base = lx + (ic * 8 + oh_l + kh) * 224 + g * 8;
      uint2 lo = *(const uint2*)base;            // 8B aligned
      unsigned d0 = lo.x, d1 = lo.y;
      unsigned d2 = *(const unsigned*)(base + 8);
      unsigned wr = lw[oc * 9 + ic * 3 + kh];
      acc[0] = dot4(d0, wr, acc[0]);
      acc[1] = dot4(alignb(d1, d0, 1), wr, acc[1]);
      acc[2] = dot4(alignb(d1, d0, 2), wr, acc[2]);
      acc[3] = dot4(alignb(d1, d0, 3), wr, acc[3]);
      acc[4] = dot4(d1, wr, acc[4]);
      acc[5] = dot4(alignb(d2, d1, 1), wr, acc[5]);
      acc[6] = dot4(alignb(d2, d1, 2), wr, acc[6]);
      acc[7] = dot4(alignb(d2, d1, 3), wr, acc[7]);
    }

    size_t off = ((size_t)((b * 32 + oc) * 222 + oh0 + oh_l)) * 224 + g * 8;
    uint4 st;
    st.x = ((unsigned)(unsigned short)acc[0]) | ((unsigned)(unsigned short)acc[1] << 16);
    st.y = ((unsigned)(unsigned short)acc[2]) | ((unsigned)(unsigned short)acc[3] << 16);
    st.z = ((unsigned)(unsigned short)acc[4]) | ((unsigned)(unsigned short)acc[5] << 16);
    st.w = ((unsigned)(unsigned short)acc[6]) | ((unsigned)(unsigned short)acc[7] << 16);
    *(uint4*)(y1acc + off) = st;

#pragma unroll
    for (int j = 0; j < 8; ++j) if (g * 8 + j < 222) mx = max(mx, acc[j]);
  }
  mx = block_maxi(max(mx, 0));
  if (!tid) atomicMax(max1, mx);
}

__global__ void k_fin1(Scal* sc, const float* __restrict__ b2, int* __restrict__ bint2) {
  float sc1 = sc->s_in * sc->sw1;
  float s1 = fmaxf((float)sc->max1 * sc1, 1e-8f) / 15.f;
  if (!threadIdx.x) sc->s1 = s1;
  float sb = s1 * sc->sw2;
  bint2[threadIdx.x] = (int)rintf(b2[threadIdx.x] / sb);
}

// int16 planar acc -> NHWC uint8 relu4 codes (32 ic bytes contiguous per pixel)
__global__ void k_requant_t(const short* __restrict__ y1acc, const Scal* __restrict__ sc,
                            unsigned char* __restrict__ y1n) {
  int p = blockIdx.x * 256 + threadIdx.x;  // pixel within image (padded space)
  int b = blockIdx.y;
  if (p >= NPIX) return;
  float sc1 = sc->s_in * sc->sw1, s1 = sc->s1;
  const short* base = y1acc + (size_t)b * 32 * NPIX + p;
  unsigned w[8] = {0, 0, 0, 0, 0, 0, 0, 0};
#pragma unroll
  for (int oc = 0; oc < 32; ++oc) {
    int a = (int)base[(size_t)oc * NPIX];
    float y = (float)a * sc1;
    float q = rintf(y / s1);
    q = fminf(fmaxf(q, 0.f), 15.f);
    w[oc >> 2] |= ((unsigned)(int)q) << (8 * (oc & 3));
  }
  uint4* dst = (uint4*)(y1n + ((size_t)b * NPIX + p) * 32);
  dst[0] = make_uint4(w[0], w[1], w[2], w[3]);
  dst[1] = make_uint4(w[4], w[5], w[6], w[7]);
}

// conv2 via MFMA i8 implicit GEMM: one wave = 32 px (along ow) x 64 oc, K = 288.
__global__ void __launch_bounds__(256) k_conv2(
    const unsigned char* __restrict__ y1n, const unsigned* __restrict__ w2pk,
    const int* __restrict__ bint2, unsigned short* __restrict__ y2, int* __restrict__ max2) {
  __shared__ unsigned lw[4608];  // 18 KB: [(tap*2+half)*64 + dl]*4 + q
  int tid = threadIdx.x;
  for (int i = tid; i < 4608; i += 256) {
    int oc = i / 72, r = i - oc * 72;
    int tap = r >> 3, icq = r & 7;
    int dl = (oc & 31) | ((icq >> 2) << 5);
    lw[(((tap * 2) + (oc >> 5)) * 64 + dl) * 4 + (icq & 3)] = w2pk[i];
  }
  __syncthreads();

  int lane = tid & 63;
  int lane31 = lane & 31, lhalf = lane >> 5;
  int wv = blockIdx.x * 4 + (tid >> 6);      // global wave id
  int owg = wv % 7; int t = wv / 7;
  int oh = t % 220; int b = t / 220;
  int ow0 = owg * 32;

  int bias0 = bint2[lane31];
  int bias1 = bint2[32 + lane31];
  v16i acc0, acc1;
#pragma unroll
  for (int r = 0; r < 16; ++r) { acc0[r] = bias0; acc1[r] = bias1; }

  size_t aoff = (size_t)lane31 * 32 + (size_t)lhalf * 16;
#pragma unroll
  for (int kh = 0; kh < 3; ++kh) {
    const unsigned char* rowb = y1n + ((size_t)((b * 222 + oh + kh) * 224 + ow0)) * 32 + aoff;
#pragma unroll
    for (int kw = 0; kw < 3; ++kw) {
      int tap = kh * 3 + kw;
      v4i a = *(const v4i*)(rowb + kw * 32);
      v4i b0 = *(const v4i*)(lw + ((tap * 2 + 0) * 64 + lane) * 4);
      v4i b1 = *(const v4i*)(lw + ((tap * 2 + 1) * 64 + lane) * 4);
      acc0 = __builtin_amdgcn_mfma_i32_32x32x32_i8(a, b0, acc0, 0, 0, 0);
      acc1 = __builtin_amdgcn_mfma_i32_32x32x32_i8(a, b1, acc1, 0, 0, 0);
    }
  }

  size_t obase = (size_t)(b * 220 + oh) * 220;
  int mx = 0;
#pragma unroll
  for (int r = 0; r < 16; ++r) {
    int m = (r & 3) + 8 * (r >> 2) + 4 * lhalf;
    int ow = ow0 + m;
    if (ow < 220) {
      int a0 = acc0[r], a1 = acc1[r];
      unsigned short* dst = y2 + (obase + ow) * 64;
      dst[lane31]      = (unsigned short)min(max(a0, 0), 65535);
      dst[32 + lane31] = (unsigned short)min(max(a1, 0), 65535);
      mx = max(mx, max(a0, a1));
    }
  }
  mx = block_maxi(max(mx, 0));
  if (!tid) atomicMax(max2, mx);
}

__global__ void k_fin2(Scal* sc) {
  sc->s2 = fmaxf((float)sc->max2 * (sc->s1 * sc->sw2), 1e-8f) / 15.f;
}

// quantize y2 (NHWC) + global average pool: int sums accumulated per (b, oc)
__global__ void k_pool(const unsigned short* __restrict__ y2, const Scal* __restrict__ sc,
                       int* __restrict__ pooled_i) {
  int b = blockIdx.x;        // 0..31
  int chunk = blockIdx.y;    // 0..10 (4400 px each, 11*4400 = 48400)
  int oc = threadIdx.x & 63;
  int pr = threadIdx.x >> 6; // 0..3
  float sc2 = sc->s1 * sc->sw2, s2 = sc->s2;
  const unsigned short* base = y2 + ((size_t)b * 48400 + (size_t)chunk * 4400) * 64 + oc;
  int sum = 0;
  for (int i = pr; i < 4400; i += 4) {
    int a = (int)base[(size_t)i * 64];
    float y = (float)a * sc2;
    float q = rintf(y / s2);
    q = fminf(fmaxf(q, 0.f), 15.f);
    sum += (int)q;
  }
  __shared__ int red[4][64];
  red[pr][oc] = sum;
  __syncthreads();
  if (pr == 0) {
    int t = red[0][oc] + red[1][oc] + red[2][oc] + red[3][oc];
    atomicAdd(&pooled_i[b * 64 + oc], t);
  }
}

// whole FC head + log_softmax in one block
__global__ void k_fc(const int* __restrict__ pooled_i, const float* __restrict__ wf1,
                     const float* __restrict__ bf1, const float* __restrict__ wf2,
                     const float* __restrict__ bf2, const Scal* __restrict__ sc,
                     float* __restrict__ out) {
  __shared__ float pl[2048];
  __shared__ float wq1[8192];
  __shared__ float y3[4096];
  __shared__ float zz[320];
  __shared__ float s3sh;
  int tid = threadIdx.x;
  float swf1 = sc->swf1, swf2 = sc->swf2, s2 = sc->s2;
  for (int i = tid; i < 2048; i += 256) pl[i] = (float)pooled_i[i] * s2 / 48400.0f;
  for (int i = tid; i < 8192; i += 256) {
    float q = rintf(wf1[i] / swf1);
    q = fminf(fmaxf(q, -8.f), 7.f);
    wq1[i] = q * swf1;
  }
  __syncthreads();
  float sb1 = s2 * swf1;
  float lmax = 0.f;
  for (int o = tid; o < 4096; o += 256) {
    int b = o >> 7, j = o & 127;
    float acc = rintf(bf1[j] / sb1) * sb1;
    const float* wrow = &wq1[j * 64];
    const float* xrow = &pl[b * 64];
#pragma unroll 16
    for (int k = 0; k < 64; ++k) acc += xrow[k] * wrow[k];
    float r = fmaxf(acc, 0.f);
    y3[o] = r;
    lmax = fmaxf(lmax, r);
  }
  float m = block_maxf(lmax);  // contains a __syncthreads (after y3 writes)
  if (!tid) s3sh = fmaxf(m, 1e-8f) / 15.f;
  __syncthreads();
  float s3 = s3sh;
  float sb2 = s3 * swf2;
  for (int o = tid; o < 320; o += 256) {
    int b = o / 10, j = o - b * 10;
    float acc = rintf(bf2[j] / sb2) * sb2;
    const float* yy = &y3[b * 128];
    const float* wrow = &wf2[j * 128];
    for (int k = 0; k < 128; ++k) {
      float q = rintf(yy[k] / s3);
      q = fminf(fmaxf(q, 0.f), 15.f);
      float wv = rintf(wrow[k] / swf2);
      wv = fminf(fmaxf(wv, -8.f), 7.f);
      acc += (q * s3) * (wv * swf2);
    }
    zz[o] = acc;
  }
  __syncthreads();
  if (tid < 32) {
    const float* z = &zz[tid * 10];
    float mm = z[0];
    for (int k = 1; k < 10; ++k) mm = fmaxf(mm, z[k]);
    float ssum = 0.f;
    for (int k = 0; k < 10; ++k) ssum += expf(z[k] - mm);
    float l = mm + logf(ssum);
    for (int k = 0; k < 10; ++k) out[tid * 10 + k] = z[k] - l;
  }
}

extern "C" void kernel_launch(void* const* d_in, const int* in_sizes, int n_in,
                              void* d_out, int out_size, void* d_ws, size_t ws_size,
                              hipStream_t stream) {
  const float* x   = (const float*)d_in[0];
  const float* w1  = (const float*)d_in[1];
  const float* b1  = (const float*)d_in[2];
  const float* w2  = (const float*)d_in[3];
  const float* b2  = (const float*)d_in[4];
  const float* wf1 = (const float*)d_in[5];
  const float* bf1 = (const float*)d_in[6];
  const float* wf2 = (const float*)d_in[7];
  const float* bf2 = (const float*)d_in[8];
  float* out = (float*)d_out;

  char* ws = (char*)d_ws;
  Scal* sc = (Scal*)ws;
  size_t off = 1024;
  signed char* xq = (signed char*)(ws + off);   off += (size_t)NX + 256;  // +slack
  off = (off + 255) & ~(size_t)255;
  unsigned* w1pk = (unsigned*)(ws + off);       off += 2048;              // [oc][row] {w0,w1,w2,0}
  unsigned* w2pk = (unsigned*)(ws + off);       off += 4608 * 4;          // [oc][kh][kw][ic/4]
  int* bint1 = (int*)(ws + off);                off += 256;
  int* bint2 = (int*)(ws + off);                off += 256;
  unsigned char* y1n = (unsigned char*)(ws + off); off += (size_t)NP1;    // NHWC codes
  off = (off + 255) & ~(size_t)255;
  int* pooled_i = (int*)(ws + off);             off += 8192;              // also slack for conv2 tail reads
  // y2 region (198 MB, NHWC u16) doubles as y1acc (102 MB) — y1acc fully consumed before conv2 writes y2
  unsigned short* y2 = (unsigned short*)(ws + off);
  short* y1acc = (short*)(ws + off);            off += (size_t)32 * 220 * 220 * 64 * 2;
  (void)ws_size; (void)in_sizes; (void)n_in; (void)out_size;

  hipMemsetAsync(sc, 0, 1024, stream);
  hipMemsetAsync(pooled_i, 0, 8192, stream);
  k_absmax_x<<<1024, 256, 0, stream>>>((const float4*)x, NX / 4, &sc->max_x);
  k_absmax_w<<<4, 256, 0, stream>>>(w1, w2, wf1, wf2, sc);
  k_scales<<<1, 1, 0, stream>>>(sc);
  k_quant_x<<<NX / 4 / 256, 256, 0, stream>>>((const float4*)x, (unsigned*)xq, NX / 4, sc);
  k_quant_w<<<22, 256, 0, stream>>>(w1, w2, b1, sc, w1pk, w2pk, bint1);
  k_conv1<<<dim3(37, 32), 256, 0, stream>>>(xq, w1pk, bint1, y1acc, &sc->max1);
  k_fin1<<<1, 64, 0, stream>>>(sc, b2, bint2);
  k_requant_t<<<dim3(195, 32), 256, 0, stream>>>(y1acc, sc, y1n);
  k_conv2<<<NW2 / 4, 256, 0, stream>>>(y1n, w2pk, bint2, y2, &sc->max2);
  k_fin2<<<1, 1, 0, stream>>>(sc);
  k_pool<<<dim3(32, 11), 256, 0, stream>>>(y2, sc, pooled_i);
  k_fc<<<1, 256, 0, stream>>>(pooled_i, wf1, bf1, wf2, bf2, sc, out);
}

// Round 8
// 467.400 us; speedup vs baseline: 4.9468x; 1.4054x over previous
//
#include <hip/hip_runtime.h>
#include <cstdint>
#include <cstddef>

#define DI __device__ __forceinline__

typedef int v4i  __attribute__((ext_vector_type(4)));
typedef int v16i __attribute__((ext_vector_type(16)));

#if defined(__has_builtin)
#if __has_builtin(__builtin_amdgcn_sdot4)
#define HAS_SDOT4 1
#endif
#if __has_builtin(__builtin_amdgcn_alignbyte)
#define HAS_ALIGNBYTE 1
#endif
#endif

DI int dot4(unsigned a, unsigned b, int c) {
#ifdef HAS_SDOT4
  return __builtin_amdgcn_sdot4((int)a, (int)b, c, false);
#else
#pragma unroll
  for (int k = 0; k < 4; ++k)
    c += (int)(signed char)(a >> (8 * k)) * (int)(signed char)(b >> (8 * k));
  return c;
#endif
}

DI unsigned alignb(unsigned hi, unsigned lo, int sh) {  // bytes (hi:lo) >> 8*sh
#ifdef HAS_ALIGNBYTE
  return __builtin_amdgcn_alignbyte(hi, lo, sh);
#else
  return (lo >> (8 * sh)) | (hi << (32 - 8 * sh));
#endif
}

// ---------------- scalar block in workspace ----------------
struct Scal {
  unsigned max_x, max_w1, max_w2, max_wf1, max_wf2;  // float bits (abs-max, >=0)
  float s_in, sw1, sw2, swf1, swf2;
  int   max1; float s1;
  int   max2; float s2;
};

static constexpr int NX   = 32 * 3 * 224 * 224;     // 4,816,896
static constexpr int NP1  = 32 * 32 * 222 * 224;    // 50,921,472 padded conv1 outputs
static constexpr int NPIX = 222 * 224;              // 49,728 padded pixels per image
static constexpr int NW2 = 32 * 220 * 7;            // conv2 waves: 32 px x 64 oc tiles

// ---------------- reduction helpers (blockDim == 256) ----------------
DI float wave_maxf(float v) { for (int o = 32; o; o >>= 1) v = fmaxf(v, __shfl_down(v, o, 64)); return v; }
DI int   wave_maxi(int v)   { for (int o = 32; o; o >>= 1) v = max(v, __shfl_down(v, o, 64));   return v; }

DI float block_maxf(float v) {  // valid in thread 0; all values >= 0
  __shared__ float s[4];
  v = wave_maxf(v);
  int lane = threadIdx.x & 63, w = threadIdx.x >> 6;
  if (!lane) s[w] = v;
  __syncthreads();
  if (threadIdx.x < 64) {
    float t = (threadIdx.x < 4) ? s[threadIdx.x] : 0.f;
    v = wave_maxf(t);
  }
  return v;
}

DI int block_maxi(int v) {  // valid in thread 0; all values >= 0
  __shared__ int s[4];
  v = wave_maxi(v);
  int lane = threadIdx.x & 63, w = threadIdx.x >> 6;
  if (!lane) s[w] = v;
  __syncthreads();
  if (threadIdx.x < 64) {
    int t = (threadIdx.x < 4) ? s[threadIdx.x] : 0;
    v = wave_maxi(t);
  }
  return v;
}

// ---------------- stage kernels ----------------
__global__ void k_absmax_x(const float4* __restrict__ x, int n4, unsigned* slot) {
  float m = 0.f;
  for (int i = blockIdx.x * blockDim.x + threadIdx.x; i < n4; i += gridDim.x * blockDim.x) {
    float4 v = x[i];
    m = fmaxf(m, fmaxf(fmaxf(fabsf(v.x), fabsf(v.y)), fmaxf(fabsf(v.z), fabsf(v.w))));
  }
  m = block_maxf(m);
  if (!threadIdx.x) atomicMax(slot, __float_as_uint(m));
}

__global__ void k_absmax_w(const float* __restrict__ w1, const float* __restrict__ w2,
                           const float* __restrict__ wf1, const float* __restrict__ wf2,
                           Scal* sc) {
  const float* p; int n; unsigned* slot;
  if (blockIdx.x == 0)      { p = w1;  n = 864;   slot = &sc->max_w1; }
  else if (blockIdx.x == 1) { p = w2;  n = 18432; slot = &sc->max_w2; }
  else if (blockIdx.x == 2) { p = wf1; n = 8192;  slot = &sc->max_wf1; }
  else                      { p = wf2; n = 1280;  slot = &sc->max_wf2; }
  float m = 0.f;
  for (int i = threadIdx.x; i < n; i += blockDim.x) m = fmaxf(m, fabsf(p[i]));
  m = block_maxf(m);
  if (!threadIdx.x) atomicMax(slot, __float_as_uint(m));
}

__global__ void k_scales(Scal* sc) {
  sc->s_in = fmaxf(__uint_as_float(sc->max_x),  1e-8f) / 7.f;
  sc->sw1  = fmaxf(__uint_as_float(sc->max_w1), 1e-8f) / 7.f;
  sc->sw2  = fmaxf(__uint_as_float(sc->max_w2), 1e-8f) / 7.f;
  sc->swf1 = fmaxf(__uint_as_float(sc->max_wf1),1e-8f) / 7.f;
  sc->swf2 = fmaxf(__uint_as_float(sc->max_wf2),1e-8f) / 7.f;
}

// 4 floats -> 4 packed int8 codes per thread
__global__ void k_quant_x(const float4* __restrict__ x, unsigned* __restrict__ xq,
                          int n4, const Scal* __restrict__ sc) {
  float s = sc->s_in;
  int i = blockIdx.x * 256 + threadIdx.x;
  if (i >= n4) return;
  float4 v = x[i];
  float f[4] = {v.x, v.y, v.z, v.w};
  unsigned w = 0;
#pragma unroll
  for (int k = 0; k < 4; ++k) {
    float q = rintf(f[k] / s);
    q = fminf(fmaxf(q, -8.f), 7.f);
    w |= ((unsigned)((int)q & 255)) << (8 * k);
  }
  xq[i] = w;
}

// pack w1 as [oc][row] dwords {w0,w1,w2,0}; w2 as [oc][kh][kw][ic/4] dwords; bias1 ints
__global__ void k_quant_w(const float* __restrict__ w1, const float* __restrict__ w2,
                          const float* __restrict__ b1, const Scal* __restrict__ sc,
                          unsigned* __restrict__ w1pk, unsigned* __restrict__ w2pk,
                          int* __restrict__ bint1) {
  int i = blockIdx.x * blockDim.x + threadIdx.x;
  if (i < 288) {
    int oc = i / 9, r = i - oc * 9;   // r = ic*3 + kh; bytes = kw 0..2
    float s = sc->sw1;
    unsigned w = 0;
#pragma unroll
    for (int k = 0; k < 3; ++k) {
      float q = rintf(w1[oc * 27 + r * 3 + k] / s);
      q = fminf(fmaxf(q, -8.f), 7.f);
      w |= ((unsigned)((int)q & 255)) << (8 * k);
    }
    w1pk[i] = w;
  } else if (i < 288 + 4608) {
    int j = i - 288;           // output dword index
    int d = j & 7; int t = j >> 3;
    int kw = t % 3; t /= 3;
    int kh = t % 3; int oc = t / 3;
    float s = sc->sw2;
    unsigned w = 0;
#pragma unroll
    for (int k = 0; k < 4; ++k) {
      int ic = d * 4 + k;
      float q = rintf(w2[(oc * 32 + ic) * 9 + kh * 3 + kw] / s);
      q = fminf(fmaxf(q, -8.f), 7.f);
      w |= ((unsigned)((int)q & 255)) << (8 * k);
    }
    w2pk[j] = w;
  } else if (i < 288 + 4608 + 32) {
    int j = i - 4896;
    bint1[j] = (int)rintf(b1[j] / (sc->s_in * sc->sw1));
  }
}

// conv1 LDS-tiled: one block = (b, strip of 6 oh rows). Stage 3 ic x 8 input
// rows (5.3 KB) + weights + bias in LDS once; 256 threads sweep 28 g x 6 oh x
// 32 oc tasks (21 iters) with sdot4+alignbyte on LDS segments. Stores planar
// int16 acc; block max of relu(acc) over valid cols.
__global__ void __launch_bounds__(256) k_conv1(
    const signed char* __restrict__ xq, const unsigned* __restrict__ w1pk,
    const int* __restrict__ bint1, short* __restrict__ y1acc, int* __restrict__ max1) {
  __shared__ signed char lx[3 * 8 * 224 + 16];  // [ic][row 0..7][224] + pad
  __shared__ unsigned lw[288];
  __shared__ int lb[32];
  int tid = threadIdx.x;
  int strip = blockIdx.x;   // 0..36 (222 = 6*37)
  int b = blockIdx.y;       // 0..31
  int oh0 = strip * 6;

  for (int i = tid; i < 288; i += 256) lw[i] = w1pk[i];
  if (tid < 32) lb[tid] = bint1[tid];
  {
    const unsigned* src = (const unsigned*)(xq + (size_t)b * 3 * 224 * 224);
    unsigned* dst = (unsigned*)lx;
    // 24 rows x 56 dwords = 1344 dwords, coalesced
#pragma unroll
    for (int it = 0; it < 6; ++it) {
      int i = it * 256 + tid;
      if (i < 1344) {
        int row = i / 56, d = i - row * 56;   // row = ic*8 + r
        int ic = row >> 3, r = row & 7;
        dst[i] = src[(ic * 224 + (oh0 + r)) * 56 + d];
      }
    }
  }
  __syncthreads();

  int mx = 0;
  for (int it = 0; it < 21; ++it) {
    int i = it * 256 + tid;          // 5376 tasks: g fast, then oh_l, then oc
    int g = i % 28;
    int r = i / 28;
    int oh_l = r % 6;
    int oc = r / 6;

    int bias = lb[oc];
    int acc[8];
#pragma unroll
    for (int j = 0; j < 8; ++j) acc[j] = bias;

#pragma unroll
    for (int seg = 0; seg < 9; ++seg) {
      int ic = seg / 3, kh = seg - ic * 3;
      const signed char* base = lx + (ic * 8 + oh_l + kh) * 224 + g * 8;
      uint2 lo = *(const uint2*)base;            // 8B aligned
      unsigned d0 = lo.x, d1 = lo.y;
      unsigned d2 = *(const unsigned*)(base + 8);
      unsigned wr = lw[oc * 9 + ic * 3 + kh];
      acc[0] = dot4(d0, wr, acc[0]);
      acc[1] = dot4(alignb(d1, d0, 1), wr, acc[1]);
      acc[2] = dot4(alignb(d1, d0, 2), wr, acc[2]);
      acc[3] = dot4(alignb(d1, d0, 3), wr, acc[3]);
      acc[4] = dot4(d1, wr, acc[4]);
      acc[5] = dot4(alignb(d2, d1, 1), wr, acc[5]);
      acc[6] = dot4(alignb(d2, d1, 2), wr, acc[6]);
      acc[7] = dot4(alignb(d2, d1, 3), wr, acc[7]);
    }

    size_t off = ((size_t)((b * 32 + oc) * 222 + oh0 + oh_l)) * 224 + g * 8;
    uint4 st;
    st.x = ((unsigned)(unsigned short)acc[0]) | ((unsigned)(unsigned short)acc[1] << 16);
    st.y = ((unsigned)(unsigned short)acc[2]) | ((unsigned)(unsigned short)acc[3] << 16);
    st.z = ((unsigned)(unsigned short)acc[4]) | ((unsigned)(unsigned short)acc[5] << 16);
    st.w = ((unsigned)(unsigned short)acc[6]) | ((unsigned)(unsigned short)acc[7] << 16);
    *(uint4*)(y1acc + off) = st;

#pragma unroll
    for (int j = 0; j < 8; ++j) if (g * 8 + j < 222) mx = max(mx, acc[j]);
  }
  mx = block_maxi(max(mx, 0));
  if (!tid) atomicMax(max1, mx);
}

__global__ void k_fin1(Scal* sc, const float* __restrict__ b2, int* __restrict__ bint2) {
  float sc1 = sc->s_in * sc->sw1;
  float s1 = fmaxf((float)sc->max1 * sc1, 1e-8f) / 15.f;
  if (!threadIdx.x) sc->s1 = s1;
  float sb = s1 * sc->sw2;
  bint2[threadIdx.x] = (int)rintf(b2[threadIdx.x] / sb);
}

// int16 planar acc -> NHWC uint8 relu4 codes (32 ic bytes contiguous per pixel)
__global__ void k_requant_t(const short* __restrict__ y1acc, const Scal* __restrict__ sc,
                            unsigned char* __restrict__ y1n) {
  int p = blockIdx.x * 256 + threadIdx.x;  // pixel within image (padded space)
  int b = blockIdx.y;
  if (p >= NPIX) return;
  float sc1 = sc->s_in * sc->sw1, s1 = sc->s1;
  const short* base = y1acc + (size_t)b * 32 * NPIX + p;
  unsigned w[8] = {0, 0, 0, 0, 0, 0, 0, 0};
#pragma unroll
  for (int oc = 0; oc < 32; ++oc) {
    int a = (int)base[(size_t)oc * NPIX];
    float y = (float)a * sc1;
    float q = rintf(y / s1);
    q = fminf(fmaxf(q, 0.f), 15.f);
    w[oc >> 2] |= ((unsigned)(int)q) << (8 * (oc & 3));
  }
  uint4* dst = (uint4*)(y1n + ((size_t)b * NPIX + p) * 32);
  dst[0] = make_uint4(w[0], w[1], w[2], w[3]);
  dst[1] = make_uint4(w[4], w[5], w[6], w[7]);
}

// conv2 via MFMA i8 implicit GEMM: one wave = 32 px (along ow) x 64 oc, K = 288.
__global__ void __launch_bounds__(256) k_conv2(
    const unsigned char* __restrict__ y1n, const unsigned* __restrict__ w2pk,
    const int* __restrict__ bint2, unsigned short* __restrict__ y2, int* __restrict__ max2) {
  __shared__ unsigned lw[4608];  // 18 KB: [(tap*2+half)*64 + dl]*4 + q
  int tid = threadIdx.x;
  for (int i = tid; i < 4608; i += 256) {
    int oc = i / 72, r = i - oc * 72;
    int tap = r >> 3, icq = r & 7;
    int dl = (oc & 31) | ((icq >> 2) << 5);
    lw[(((tap * 2) + (oc >> 5)) * 64 + dl) * 4 + (icq & 3)] = w2pk[i];
  }
  __syncthreads();

  int lane = tid & 63;
  int lane31 = lane & 31, lhalf = lane >> 5;
  int wv = blockIdx.x * 4 + (tid >> 6);      // global wave id
  int owg = wv % 7; int t = wv / 7;
  int oh = t % 220; int b = t / 220;
  int ow0 = owg * 32;

  int bias0 = bint2[lane31];
  int bias1 = bint2[32 + lane31];
  v16i acc0, acc1;
#pragma unroll
  for (int r = 0; r < 16; ++r) { acc0[r] = bias0; acc1[r] = bias1; }

  size_t aoff = (size_t)lane31 * 32 + (size_t)lhalf * 16;
#pragma unroll
  for (int kh = 0; kh < 3; ++kh) {
    const unsigned char* rowb = y1n + ((size_t)((b * 222 + oh + kh) * 224 + ow0)) * 32 + aoff;
#pragma unroll
    for (int kw = 0; kw < 3; ++kw) {
      int tap = kh * 3 + kw;
      v4i a = *(const v4i*)(rowb + kw * 32);
      v4i b0 = *(const v4i*)(lw + ((tap * 2 + 0) * 64 + lane) * 4);
      v4i b1 = *(const v4i*)(lw + ((tap * 2 + 1) * 64 + lane) * 4);
      acc0 = __builtin_amdgcn_mfma_i32_32x32x32_i8(a, b0, acc0, 0, 0, 0);
      acc1 = __builtin_amdgcn_mfma_i32_32x32x32_i8(a, b1, acc1, 0, 0, 0);
    }
  }

  size_t obase = (size_t)(b * 220 + oh) * 220;
  int mx = 0;
#pragma unroll
  for (int r = 0; r < 16; ++r) {
    int m = (r & 3) + 8 * (r >> 2) + 4 * lhalf;
    int ow = ow0 + m;
    if (ow < 220) {
      int a0 = acc0[r], a1 = acc1[r];
      unsigned short* dst = y2 + (obase + ow) * 64;
      dst[lane31]      = (unsigned short)min(max(a0, 0), 65535);
      dst[32 + lane31] = (unsigned short)min(max(a1, 0), 65535);
      mx = max(mx, max(a0, a1));
    }
  }
  mx = block_maxi(max(mx, 0));
  if (!tid) atomicMax(max2, mx);
}

__global__ void k_fin2(Scal* sc) {
  sc->s2 = fmaxf((float)sc->max2 * (sc->s1 * sc->sw2), 1e-8f) / 15.f;
}

// quantize y2 (NHWC) + avg pool. Fully coalesced: wave-load = 1024B contiguous
// (o8 = tid&7 spans one pixel's 64 ocs with 8 lanes x uint4; pgrp = tid>>3
// spans 8 pixels). 6 VALU/elem via q = min(rndne(a*h), 15), h = sc2/s2.
// Per-thread float sums are exact small ints; LDS-reduce, one atomic per oc.
__global__ void __launch_bounds__(256) k_pool(
    const unsigned short* __restrict__ y2, const Scal* __restrict__ sc,
    int* __restrict__ pooled_i) {
  int b = blockIdx.y;        // 0..31
  int chunk = blockIdx.x;    // 0..49, 968 px each
  int tid = threadIdx.x;
  int o8 = tid & 7;          // oc octet
  int pgrp = tid >> 3;       // 0..31
  float h = (sc->s1 * sc->sw2) * (1.0f / sc->s2);
  const unsigned short* base = y2 + ((size_t)b * 48400) * 64 + (size_t)o8 * 8;
  float sum[8] = {0.f, 0.f, 0.f, 0.f, 0.f, 0.f, 0.f, 0.f};
  int pend = chunk * 968 + 968;
  for (int p = chunk * 968 + pgrp; p < pend; p += 32) {
    uint4 v = *(const uint4*)(base + (size_t)p * 64);
    unsigned words[4] = {v.x, v.y, v.z, v.w};
#pragma unroll
    for (int k = 0; k < 8; ++k) {
      int a = (int)(unsigned short)(words[k >> 1] >> (16 * (k & 1)));
      float q = fminf(rintf((float)a * h), 15.f);
      sum[k] += q;
    }
  }
  __shared__ float red[32][64];
#pragma unroll
  for (int j = 0; j < 8; ++j) red[pgrp][o8 * 8 + j] = sum[j];
  __syncthreads();
  if (tid < 64) {
    float t = 0.f;
#pragma unroll 8
    for (int pg = 0; pg < 32; ++pg) t += red[pg][tid];
    atomicAdd(&pooled_i[b * 64 + tid], (int)t);
  }
}

// whole FC head + log_softmax in one block
__global__ void k_fc(const int* __restrict__ pooled_i, const float* __restrict__ wf1,
                     const float* __restrict__ bf1, const float* __restrict__ wf2,
                     const float* __restrict__ bf2, const Scal* __restrict__ sc,
                     float* __restrict__ out) {
  __shared__ float pl[2048];
  __shared__ float wq1[8192];
  __shared__ float y3[4096];
  __shared__ float zz[320];
  __shared__ float s3sh;
  int tid = threadIdx.x;
  float swf1 = sc->swf1, swf2 = sc->swf2, s2 = sc->s2;
  for (int i = tid; i < 2048; i += 256) pl[i] = (float)pooled_i[i] * s2 / 48400.0f;
  for (int i = tid; i < 8192; i += 256) {
    float q = rintf(wf1[i] / swf1);
    q = fminf(fmaxf(q, -8.f), 7.f);
    wq1[i] = q * swf1;
  }
  __syncthreads();
  float sb1 = s2 * swf1;
  float lmax = 0.f;
  for (int o = tid; o < 4096; o += 256) {
    int b = o >> 7, j = o & 127;
    float acc = rintf(bf1[j] / sb1) * sb1;
    const float* wrow = &wq1[j * 64];
    const float* xrow = &pl[b * 64];
#pragma unroll 16
    for (int k = 0; k < 64; ++k) acc += xrow[k] * wrow[k];
    float r = fmaxf(acc, 0.f);
    y3[o] = r;
    lmax = fmaxf(lmax, r);
  }
  float m = block_maxf(lmax);  // contains a __syncthreads (after y3 writes)
  if (!tid) s3sh = fmaxf(m, 1e-8f) / 15.f;
  __syncthreads();
  float s3 = s3sh;
  float sb2 = s3 * swf2;
  for (int o = tid; o < 320; o += 256) {
    int b = o / 10, j = o - b * 10;
    float acc = rintf(bf2[j] / sb2) * sb2;
    const float* yy = &y3[b * 128];
    const float* wrow = &wf2[j * 128];
    for (int k = 0; k < 128; ++k) {
      float q = rintf(yy[k] / s3);
      q = fminf(fmaxf(q, 0.f), 15.f);
      float wv = rintf(wrow[k] / swf2);
      wv = fminf(fmaxf(wv, -8.f), 7.f);
      acc += (q * s3) * (wv * swf2);
    }
    zz[o] = acc;
  }
  __syncthreads();
  if (tid < 32) {
    const float* z = &zz[tid * 10];
    float mm = z[0];
    for (int k = 1; k < 10; ++k) mm = fmaxf(mm, z[k]);
    float ssum = 0.f;
    for (int k = 0; k < 10; ++k) ssum += expf(z[k] - mm);
    float l = mm + logf(ssum);
    for (int k = 0; k < 10; ++k) out[tid * 10 + k] = z[k] - l;
  }
}

extern "C" void kernel_launch(void* const* d_in, const int* in_sizes, int n_in,
                              void* d_out, int out_size, void* d_ws, size_t ws_size,
                              hipStream_t stream) {
  const float* x   = (const float*)d_in[0];
  const float* w1  = (const float*)d_in[1];
  const float* b1  = (const float*)d_in[2];
  const float* w2  = (const float*)d_in[3];
  const float* b2  = (const float*)d_in[4];
  const float* wf1 = (const float*)d_in[5];
  const float* bf1 = (const float*)d_in[6];
  const float* wf2 = (const float*)d_in[7];
  const float* bf2 = (const float*)d_in[8];
  float* out = (float*)d_out;

  char* ws = (char*)d_ws;
  Scal* sc = (Scal*)ws;
  size_t off = 1024;
  signed char* xq = (signed char*)(ws + off);   off += (size_t)NX + 256;  // +slack
  off = (off + 255) & ~(size_t)255;
  unsigned* w1pk = (unsigned*)(ws + off);       off += 2048;              // [oc][row] {w0,w1,w2,0}
  unsigned* w2pk = (unsigned*)(ws + off);       off += 4608 * 4;          // [oc][kh][kw][ic/4]
  int* bint1 = (int*)(ws + off);                off += 256;
  int* bint2 = (int*)(ws + off);                off += 256;
  unsigned char* y1n = (unsigned char*)(ws + off); off += (size_t)NP1;    // NHWC codes
  off = (off + 255) & ~(size_t)255;
  int* pooled_i = (int*)(ws + off);             off += 8192;              // also slack for conv2 tail reads
  // y2 region (198 MB, NHWC u16) doubles as y1acc (102 MB) — y1acc fully consumed before conv2 writes y2
  unsigned short* y2 = (unsigned short*)(ws + off);
  short* y1acc = (short*)(ws + off);            off += (size_t)32 * 220 * 220 * 64 * 2;
  (void)ws_size; (void)in_sizes; (void)n_in; (void)out_size;

  hipMemsetAsync(sc, 0, 1024, stream);
  hipMemsetAsync(pooled_i, 0, 8192, stream);
  k_absmax_x<<<1024, 256, 0, stream>>>((const float4*)x, NX / 4, &sc->max_x);
  k_absmax_w<<<4, 256, 0, stream>>>(w1, w2, wf1, wf2, sc);
  k_scales<<<1, 1, 0, stream>>>(sc);
  k_quant_x<<<NX / 4 / 256, 256, 0, stream>>>((const float4*)x, (unsigned*)xq, NX / 4, sc);
  k_quant_w<<<22, 256, 0, stream>>>(w1, w2, b1, sc, w1pk, w2pk, bint1);
  k_conv1<<<dim3(37, 32), 256, 0, stream>>>(xq, w1pk, bint1, y1acc, &sc->max1);
  k_fin1<<<1, 64, 0, stream>>>(sc, b2, bint2);
  k_requant_t<<<dim3(195, 32), 256, 0, stream>>>(y1acc, sc, y1n);
  k_conv2<<<NW2 / 4, 256, 0, stream>>>(y1n, w2pk, bint2, y2, &sc->max2);
  k_fin2<<<1, 1, 0, stream>>>(sc);
  k_pool<<<dim3(50, 32), 256, 0, stream>>>(y2, sc, pooled_i);
  k_fc<<<1, 256, 0, stream>>>(pooled_i, wf1, bf1, wf2, bf2, sc, out);
}